// Round 3
// baseline (385.980 us; speedup 1.0000x reference)
//
#include <hip/hip_runtime.h>
#include <stdint.h>

// ContextAttention: B=4, S=4096, D=512.
// Round 12: reg-cap-aware redesign. The 128-reg/wave default cap (launch_bounds
// banned) pins wave tiles at 64x64 -> 8-phase/256^2 @16 waves was null (r11:
// 130us, MfmaUtil 22%). Revert to the PROVEN 2-phase m97 core, improve its
// economics: qkt+pv now 256(M)x128(N) @ 512thr/8waves (4Mx2N), BK=32 -> 0.75x
// staged bytes/output, half the barriers/output, 2 blocks/CU. XCD-chunked
// bijective swizzle (T1) on qkt (K-slab L2-resident) and pv (P fetched ~once).
// proj_fast / convert / fallbacks unchanged.
// BANNED: __launch_bounds__ (crash-assoc rounds 1-3). All grids 1-D.

#define BDIM 4
#define SDIM 4096
#define DDIM 512
#define MROWS (BDIM * SDIM)  // 16384
#define XB_ELEMS ((size_t)MROWS * DDIM)        // 8388608
#define W_ELEMS ((size_t)DDIM * DDIM)          // 262144

typedef short short8_t __attribute__((ext_vector_type(8)));
typedef short short4_t __attribute__((ext_vector_type(4)));
typedef float float4_t __attribute__((ext_vector_type(4)));

typedef __attribute__((address_space(1))) void gvoid_t;
typedef __attribute__((address_space(3))) void lvoid_t;

__device__ __forceinline__ short f2bf(float f) {
    union { float f; uint32_t u; } v; v.f = f;
    uint32_t r = v.u + 0x7FFFu + ((v.u >> 16) & 1u);  // RNE
    return (short)(r >> 16);
}
__device__ __forceinline__ float bf2f(short s) {
    union { uint32_t u; float f; } v; v.u = ((uint32_t)(uint16_t)s) << 16;
    return v.f;
}

// Storage-dtype vote (proven).
__global__ void detect_kernel(const uint32_t* __restrict__ tok, int* __restrict__ flag) {
    __shared__ int red[256];
    const int tid = threadIdx.x;
    int c = 0;
    for (int i = tid; i < 4096; i += 256) {
        uint32_t e = (tok[i] >> 7) & 0xFFu;
        c += (e >= 105u && e <= 135u) ? 1 : 0;
    }
    red[tid] = c;
    __syncthreads();
    for (int s = 128; s > 0; s >>= 1) {
        if (tid < s) red[tid] += red[tid + s];
        __syncthreads();
    }
    if (tid == 0) *flag = (red[0] > 2048) ? 1 : 0;  // 1 = bf16 storage
}

__global__ void zero_rs_kernel(float* __restrict__ RS) {
    RS[blockIdx.x * 256 + threadIdx.x] = 0.f;
}

// Pre-convert inputs to bf16: dst = Xb[8388608] | W1b | W2b | W3b (262144 ea).
__global__ void convert_kernel(const void* __restrict__ X, const void* __restrict__ W1,
                               const void* __restrict__ W2, const void* __restrict__ W3,
                               short* __restrict__ dst, const int* __restrict__ flagp)
{
    const int bf16in = *flagp;
    const size_t i4 = ((size_t)blockIdx.x * 256 + threadIdx.x) * 4;  // elem index
    const void* src; size_t off;
    if (i4 < XB_ELEMS) { src = X; off = i4; }
    else {
        const size_t j = i4 - XB_ELEMS;
        const int g = (int)(j / W_ELEMS);
        src = (g == 0) ? W1 : (g == 1) ? W2 : W3;
        off = j - (size_t)g * W_ELEMS;
    }
    if (bf16in) {
        *(short4_t*)(dst + i4) = *(const short4_t*)((const short*)src + off);
    } else {
        float4 v = *(const float4*)((const float*)src + off);
        short4_t s = { f2bf(v.x), f2bf(v.y), f2bf(v.z), f2bf(v.w) };
        *(short4_t*)(dst + i4) = s;
    }
}

// ---------------- m97-style GEMM core, 128x128 @256thr (proj) ----------------
__device__ __forceinline__ void gemm_core(
    const short* __restrict__ A, int lda,
    const short* __restrict__ B, int ldb,
    int m0, int n0, int kIters,
    short* As, short* Bs, float4_t acc[4][4])
{
    const int tid = threadIdx.x;
    const int w = tid >> 6, lane = tid & 63, quad = lane >> 4, l16 = lane & 15;
    const int wm = w >> 1, wn = w & 1;
    const int rsub = lane >> 2;          // row within 16-row chunk
    const int col8 = 8 * (lane & 3);     // 8-elem (16B) column chunk

    for (int kk = 0; kk < kIters; ++kk) {
        const int k0 = 32 * kk;
        __syncthreads();
#pragma unroll
        for (int c = 0; c < 2; ++c) {
            const int row = 32 * w + 16 * c + rsub;
            const short* g = A + (size_t)(m0 + row) * lda + k0 + col8;
            __builtin_amdgcn_global_load_lds((const gvoid_t*)g,
                (lvoid_t*)(As + (32 * w + 16 * c) * 32), 16, 0, 0);
        }
#pragma unroll
        for (int c = 0; c < 2; ++c) {
            const int row = 32 * w + 16 * c + rsub;
            const short* g = B + (size_t)(n0 + row) * ldb + k0 + col8;
            __builtin_amdgcn_global_load_lds((const gvoid_t*)g,
                (lvoid_t*)(Bs + (32 * w + 16 * c) * 32), 16, 0, 0);
        }
        __syncthreads();

        short8_t af[4], bfr[4];
#pragma unroll
        for (int mt = 0; mt < 4; ++mt)
            af[mt] = *(const short8_t*)&As[(64 * wm + 16 * mt + l16) * 32 + 8 * quad];
#pragma unroll
        for (int nt = 0; nt < 4; ++nt)
            bfr[nt] = *(const short8_t*)&Bs[(64 * wn + 16 * nt + l16) * 32 + 8 * quad];
#pragma unroll
        for (int mt = 0; mt < 4; ++mt)
#pragma unroll
            for (int nt = 0; nt < 4; ++nt)
                acc[mt][nt] = __builtin_amdgcn_mfma_f32_16x16x32_bf16(af[mt], bfr[nt], acc[mt][nt], 0, 0, 0);
    }
}

// -------- wide GEMM core, 256(M)x128(N) @512thr/8waves (4Mx2N), BK=32 --------
// Same per-wave 64x64 fragment math as gemm_core; staging: A 2 loads/thread,
// B 1 load/thread (global_load_lds w16, wave-uniform base + lane*16).
__device__ __forceinline__ void gemm_core_wide(
    const short* __restrict__ A, int lda,
    const short* __restrict__ B, int ldb,
    int m0, int n0, int kIters,
    short* As /*256x32*/, short* Bs /*128x32*/, float4_t acc[4][4])
{
    const int tid = threadIdx.x;
    const int w = tid >> 6, lane = tid & 63, quad = lane >> 4, l16 = lane & 15;
    const int wm = w >> 1, wn = w & 1;   // 4M x 2N wave grid
    const int rsub = lane >> 2;          // row within 16-row chunk
    const int col8 = 8 * (lane & 3);     // 8-elem (16B) column chunk

    for (int kk = 0; kk < kIters; ++kk) {
        const int k0 = 32 * kk;
        __syncthreads();
#pragma unroll
        for (int c = 0; c < 2; ++c) {
            const int row = 128 * c + 16 * w + rsub;
            const short* g = A + (size_t)(m0 + row) * lda + k0 + col8;
            __builtin_amdgcn_global_load_lds((const gvoid_t*)g,
                (lvoid_t*)(As + (128 * c + 16 * w) * 32), 16, 0, 0);
        }
        {
            const int row = 16 * w + rsub;
            const short* g = B + (size_t)(n0 + row) * ldb + k0 + col8;
            __builtin_amdgcn_global_load_lds((const gvoid_t*)g,
                (lvoid_t*)(Bs + (16 * w) * 32), 16, 0, 0);
        }
        __syncthreads();

        short8_t af[4], bfr[4];
#pragma unroll
        for (int mt = 0; mt < 4; ++mt)
            af[mt] = *(const short8_t*)&As[(64 * wm + 16 * mt + l16) * 32 + 8 * quad];
#pragma unroll
        for (int nt = 0; nt < 4; ++nt)
            bfr[nt] = *(const short8_t*)&Bs[(64 * wn + 16 * nt + l16) * 32 + 8 * quad];
#pragma unroll
        for (int mt = 0; mt < 4; ++mt)
#pragma unroll
            for (int nt = 0; nt < 4; ++nt)
                acc[mt][nt] = __builtin_amdgcn_mfma_f32_16x16x32_bf16(af[mt], bfr[nt], acc[mt][nt], 0, 0, 0);
    }
}

// ---------------- proj (all-bf16 via Xb/Wb) ----------------
// g=0: Q = Xb @ W1b^T; g=1: K; g=2: Vt[m=e][n=bs] = W3b @ Xb^T.
__global__ void proj_fast(const short* __restrict__ XbWb, short* __restrict__ QKV)
{
    __shared__ __align__(16) short As[128 * 32];
    __shared__ __align__(16) short Bs[128 * 32];

    const short* Xb = XbWb;
    const int bid = blockIdx.x;
    const int g = bid >> 9;
    const int r = bid & 511;

    const short* Ap; const short* Bp; short* Op;
    int m0, n0, ldo;
    if (g == 2) {
        Ap = XbWb + XB_ELEMS + 2 * W_ELEMS; Bp = Xb;
        Op = QKV + 2 * (size_t)MROWS * DDIM;
        m0 = 128 * (r & 3); n0 = 128 * (r >> 2); ldo = MROWS;   // Vt[e][bs]
    } else {
        Ap = Xb; Bp = XbWb + XB_ELEMS + (size_t)g * W_ELEMS;
        Op = QKV + (size_t)g * MROWS * DDIM;
        m0 = 128 * (r >> 2); n0 = 128 * (r & 3); ldo = DDIM;    // Q/K[bs][e]
    }

    const float4_t z4 = {0.f, 0.f, 0.f, 0.f};
    float4_t acc[4][4];
#pragma unroll
    for (int i = 0; i < 4; ++i)
#pragma unroll
        for (int j = 0; j < 4; ++j) acc[i][j] = z4;

    gemm_core(Ap, DDIM, Bp, DDIM, m0, n0, 16, As, Bs, acc);

    const int tid = threadIdx.x;
    const int w = tid >> 6, lane = tid & 63, quad = lane >> 4, l16 = lane & 15;
    const int wm = w >> 1, wn = w & 1;
#pragma unroll
    for (int mt = 0; mt < 4; ++mt)
#pragma unroll
        for (int nt = 0; nt < 4; ++nt)
#pragma unroll
            for (int rr = 0; rr < 4; ++rr) {
                const int m = m0 + 64 * wm + 16 * mt + 4 * quad + rr;
                const int n = n0 + 64 * wn + 16 * nt + l16;
                Op[(size_t)m * ldo + n] = f2bf(acc[mt][nt][rr]);
            }
}

// ---------------- qkt: P = exp(sc * Q K^T) + rowsums, 256x128 tiles ---------
// 512 thr, grid nb*512 (per batch: 16 M-tiles x 32 N-tiles). XCD-chunked
// swizzle: XCD x handles logical tiles [x*G/8,(x+1)*G/8) -> K batch slab
// (4MB) L2-resident, Q panels reused.
__global__ void qkt_kernel(const short* __restrict__ QKV, short* __restrict__ P,
                           float* __restrict__ RS, int bbase)
{
    __shared__ __align__(16) short As[256 * 32];
    __shared__ __align__(16) short Bs[128 * 32];

    const int cpx = (int)(gridDim.x >> 3);          // grid % 8 == 0 (bijective)
    const int bid = (int)blockIdx.x;
    const int l = (bid & 7) * cpx + (bid >> 3);     // XCD chunk (T1)
    const int bb = l >> 9;
    const int r = l & 511;
    const int b = bbase + bb;
    const int m0 = 256 * (r >> 5);
    const int n0 = 128 * (r & 31);

    const short* Qb = QKV + (size_t)b * SDIM * DDIM;
    const short* Kb = QKV + (size_t)MROWS * DDIM + (size_t)b * SDIM * DDIM;

    const float4_t z4 = {0.f, 0.f, 0.f, 0.f};
    float4_t acc[4][4];
#pragma unroll
    for (int i = 0; i < 4; ++i)
#pragma unroll
        for (int j = 0; j < 4; ++j) acc[i][j] = z4;

    gemm_core_wide(Qb, DDIM, Kb, DDIM, m0, n0, 16, As, Bs, acc);

    const int tid = threadIdx.x;
    const int w = tid >> 6, lane = tid & 63, quad = lane >> 4, l16 = lane & 15;
    const int wm = w >> 1, wn = w & 1;
    const float kSc = 1.44269504088896341f * 0.04419417382415922f;  // log2(e)/sqrt(512)
    short* Pb = P + (size_t)bb * SDIM * SDIM;
#pragma unroll
    for (int mt = 0; mt < 4; ++mt)
#pragma unroll
        for (int rr = 0; rr < 4; ++rr) {
            const int q = m0 + 64 * wm + 16 * mt + 4 * quad + rr;
            float sum = 0.f;
#pragma unroll
            for (int nt = 0; nt < 4; ++nt) {
                const float p = exp2f(acc[mt][nt][rr] * kSc);
                const short pb = f2bf(p);
                sum += bf2f(pb);
                Pb[(size_t)q * SDIM + n0 + 64 * wn + 16 * nt + l16] = pb;
            }
            sum += __shfl_xor(sum, 1); sum += __shfl_xor(sum, 2);
            sum += __shfl_xor(sum, 4); sum += __shfl_xor(sum, 8);
            if (l16 == 0) atomicAdd(&RS[(size_t)b * SDIM + q], sum);
        }
}

// ---------------- pv: out = (P @ Vt-rows) / RS, 256x128 tiles ----------------
// 512 thr, grid nb*64 (per batch: 16 M-tiles x 4 N-tiles). XCD-chunked
// swizzle: 4 consecutive n-tiles of each P-panel stay on one XCD -> P fetched
// ~once; Vt batch slab (4MB) L2-resident.
__global__ void pv_kernel(const short* __restrict__ P, const short* __restrict__ QKV,
                          const float* __restrict__ RS, void* __restrict__ out,
                          const int* __restrict__ flagp, int bbase)
{
    __shared__ __align__(16) short As[256 * 32];
    __shared__ __align__(16) short Bs[128 * 32];

    const int bf16out = *flagp;
    const int cpx = (int)(gridDim.x >> 3);          // grid % 8 == 0
    const int bid = (int)blockIdx.x;
    const int l = (bid & 7) * cpx + (bid >> 3);     // XCD chunk (T1)
    const int bb = l >> 6;
    const int r = l & 63;
    const int b = bbase + bb;
    const int m0 = 256 * (r >> 2);
    const int n0 = 128 * (r & 3);

    const short* Pb = P + (size_t)bb * SDIM * SDIM;
    const short* Vt = QKV + 2 * (size_t)MROWS * DDIM + (size_t)b * SDIM;  // rows stride MROWS

    const float4_t z4 = {0.f, 0.f, 0.f, 0.f};
    float4_t acc[4][4];
#pragma unroll
    for (int i = 0; i < 4; ++i)
#pragma unroll
        for (int j = 0; j < 4; ++j) acc[i][j] = z4;

    gemm_core_wide(Pb, SDIM, Vt, MROWS, m0, n0, 128, As, Bs, acc);

    const int tid = threadIdx.x;
    const int w = tid >> 6, lane = tid & 63, quad = lane >> 4, l16 = lane & 15;
    const int wm = w >> 1, wn = w & 1;
#pragma unroll
    for (int mt = 0; mt < 4; ++mt)
#pragma unroll
        for (int rr = 0; rr < 4; ++rr) {
            const size_t grow = (size_t)b * SDIM + m0 + 64 * wm + 16 * mt + 4 * quad + rr;
            const float inv = 1.0f / RS[grow];
#pragma unroll
            for (int nt = 0; nt < 4; ++nt) {
                const int n = n0 + 64 * wn + 16 * nt + l16;
                const float o = acc[mt][nt][rr] * inv;
                if (bf16out) ((short*)out)[grow * DDIM + n] = f2bf(o);
                else         ((float*)out)[grow * DDIM + n] = o;
            }
        }
}

// ---------------- Fallbacks (proven round-6/8 versions) ----------------
__global__ void proj_mfma_legacy(const void* __restrict__ X, const void* __restrict__ W1,
                          const void* __restrict__ W2, const void* __restrict__ W3,
                          short* __restrict__ QKV, const int* __restrict__ flagp)
{
    __shared__ __align__(16) short As[128][40];
    __shared__ __align__(16) short Bs[128][40];

    const int bf16in = *flagp;
    const int bid = blockIdx.x;
    const int g = bid >> 9;
    const int r = bid & 511;

    const void* Ap; const void* Bp; short* Op;
    int m0, n0, ldo;
    if (g == 2) {
        Ap = W3; Bp = X; Op = QKV + 2 * (size_t)MROWS * DDIM;
        m0 = 128 * (r & 3); n0 = 128 * (r >> 2); ldo = MROWS;
    } else {
        Ap = X; Bp = (g == 0) ? W1 : W2; Op = QKV + (size_t)g * MROWS * DDIM;
        m0 = 128 * (r >> 2); n0 = 128 * (r & 3); ldo = DDIM;
    }

    const float* Af = (const float*)Ap;  const float* Bf = (const float*)Bp;
    const short* Ah = (const short*)Ap;  const short* Bh = (const short*)Bp;

    const int tid = threadIdx.x;
    const int w = tid >> 6, lane = tid & 63, quad = lane >> 4, l16 = lane & 15;
    const int wm = w >> 1, wn = w & 1;
    const int rgrp = tid >> 3, cg = tid & 7;

    const float4_t z4 = {0.f, 0.f, 0.f, 0.f};
    float4_t acc[4][4];
#pragma unroll
    for (int i = 0; i < 4; ++i)
#pragma unroll
        for (int j = 0; j < 4; ++j) acc[i][j] = z4;

    for (int kk = 0; kk < 16; ++kk) {
        const int k0 = 32 * kk;
        __syncthreads();
        if (bf16in) {
#pragma unroll
            for (int i = 0; i < 4; ++i) {
                const int row = rgrp + 32 * i;
                *(short4_t*)&As[row][4 * cg] =
                    *(const short4_t*)(Ah + (size_t)(m0 + row) * DDIM + k0 + 4 * cg);
                *(short4_t*)&Bs[row][4 * cg] =
                    *(const short4_t*)(Bh + (size_t)(n0 + row) * DDIM + k0 + 4 * cg);
            }
        } else {
#pragma unroll
            for (int i = 0; i < 4; ++i) {
                const int row = rgrp + 32 * i;
                float4 va = *(const float4*)(Af + (size_t)(m0 + row) * DDIM + k0 + 4 * cg);
                short4_t sa = { f2bf(va.x), f2bf(va.y), f2bf(va.z), f2bf(va.w) };
                *(short4_t*)&As[row][4 * cg] = sa;
                float4 vb = *(const float4*)(Bf + (size_t)(n0 + row) * DDIM + k0 + 4 * cg);
                short4_t sb = { f2bf(vb.x), f2bf(vb.y), f2bf(vb.z), f2bf(vb.w) };
                *(short4_t*)&Bs[row][4 * cg] = sb;
            }
        }
        __syncthreads();

        short8_t af[4], bfr[4];
#pragma unroll
        for (int mt = 0; mt < 4; ++mt)
            af[mt] = *(const short8_t*)&As[64 * wm + 16 * mt + l16][8 * quad];
#pragma unroll
        for (int nt = 0; nt < 4; ++nt)
            bfr[nt] = *(const short8_t*)&Bs[64 * wn + 16 * nt + l16][8 * quad];
#pragma unroll
        for (int mt = 0; mt < 4; ++mt)
#pragma unroll
            for (int nt = 0; nt < 4; ++nt)
                acc[mt][nt] = __builtin_amdgcn_mfma_f32_16x16x32_bf16(af[mt], bfr[nt], acc[mt][nt], 0, 0, 0);
    }

#pragma unroll
    for (int mt = 0; mt < 4; ++mt)
#pragma unroll
        for (int nt = 0; nt < 4; ++nt)
#pragma unroll
            for (int rr = 0; rr < 4; ++rr) {
                const int m = m0 + 64 * wm + 16 * mt + 4 * quad + rr;
                const int n = n0 + 64 * wn + 16 * nt + l16;
                Op[(size_t)m * ldo + n] = f2bf(acc[mt][nt][rr]);
            }
}

__global__ void attn_mfma(const short* __restrict__ QKV, void* __restrict__ out,
                          const int* __restrict__ flagp)
{
    __shared__ __align__(16) short Ks[32][520];
    __shared__ __align__(16) short Ps[32][72];
    __shared__ float rowsum[2][32];

    const int bf16out = *flagp;
    const short* Qb = QKV;
    const short* Kb = QKV + (size_t)MROWS * DDIM;
    const short* Vt = QKV + 2 * (size_t)MROWS * DDIM;

    const int b = blockIdx.x >> 7;
    const int q0 = (blockIdx.x & 127) * 32;
    const int tid = threadIdx.x;
    const int w = tid >> 6, lane = tid & 63, quad = lane >> 4, l16 = lane & 15;
    const int strip = w >> 1, half = w & 1;

    short8_t qf[16];
    {
        const short* qrow = Qb + (size_t)(b * SDIM + q0 + 16 * strip + l16) * DDIM + 8 * quad;
#pragma unroll
        for (int kc = 0; kc < 16; ++kc)
            qf[kc] = *(const short8_t*)(qrow + 32 * kc);
    }

    const float4_t z4 = {0.f, 0.f, 0.f, 0.f};
    float4_t o[2][8];
#pragma unroll
    for (int mt = 0; mt < 2; ++mt)
#pragma unroll
        for (int nt = 0; nt < 8; ++nt) o[mt][nt] = z4;
    float rs[4] = {0.f, 0.f, 0.f, 0.f};

    const float kSc = 1.44269504088896341f * 0.04419417382415922f;

    for (int kt = 0; kt < 128; ++kt) {
        const int kv0 = 32 * kt;
        __syncthreads();
#pragma unroll
        for (int r = 0; r < 8; ++r) {
            const int kv = 8 * w + r;
            short8_t t = *(const short8_t*)(Kb + (size_t)(b * SDIM + kv0 + kv) * DDIM + 8 * lane);
            *(short8_t*)&Ks[kv][8 * lane] = t;
        }
        __syncthreads();

        float4_t sacc = z4;
#pragma unroll
        for (int kc = 0; kc < 16; ++kc) {
            short8_t kf = *(const short8_t*)&Ks[16 * half + l16][32 * kc + 8 * quad];
            sacc = __builtin_amdgcn_mfma_f32_16x16x32_bf16(qf[kc], kf, sacc, 0, 0, 0);
        }

#pragma unroll
        for (int r = 0; r < 4; ++r) {
            const float p = exp2f(sacc[r] * kSc);
            const short pb = f2bf(p);
            rs[r] += bf2f(pb);
            Ps[16 * strip + 4 * quad + r][16 * half + l16] = pb;
        }
        __syncthreads();

        short8_t pa0 = *(const short8_t*)&Ps[l16][8 * quad];
        short8_t pa1 = *(const short8_t*)&Ps[16 + l16][8 * quad];
#pragma unroll
        for (int nt = 0; nt < 8; ++nt) {
            const short* vp = Vt + (size_t)(128 * w + 16 * nt + l16) * MROWS
                            + (b * SDIM + kv0 + 8 * quad);
            short8_t vb = *(const short8_t*)vp;
            o[0][nt] = __builtin_amdgcn_mfma_f32_16x16x32_bf16(pa0, vb, o[0][nt], 0, 0, 0);
            o[1][nt] = __builtin_amdgcn_mfma_f32_16x16x32_bf16(pa1, vb, o[1][nt], 0, 0, 0);
        }
    }

#pragma unroll
    for (int r = 0; r < 4; ++r) {
        float v = rs[r];
        v += __shfl_xor(v, 1); v += __shfl_xor(v, 2);
        v += __shfl_xor(v, 4); v += __shfl_xor(v, 8);
        rs[r] = v;
    }
    if (l16 == 0) {
#pragma unroll
        for (int r = 0; r < 4; ++r)
            rowsum[half][16 * strip + 4 * quad + r] = rs[r];
    }
    __syncthreads();

#pragma unroll
    for (int mt = 0; mt < 2; ++mt)
#pragma unroll
        for (int r = 0; r < 4; ++r) {
            const int q = 16 * mt + 4 * quad + r;
            const float inv = 1.0f / (rowsum[0][q] + rowsum[1][q]);
            const size_t base = (size_t)(b * SDIM + q0 + q) * DDIM + 128 * w + l16;
            if (bf16out) {
                short* orow = (short*)out + base;
#pragma unroll
                for (int nt = 0; nt < 8; ++nt)
                    orow[16 * nt] = f2bf(o[mt][nt][r] * inv);
            } else {
                float* orow = (float*)out + base;
#pragma unroll
                for (int nt = 0; nt < 8; ++nt)
                    orow[16 * nt] = o[mt][nt][r] * inv;
            }
        }
}

__global__ void zero_out_kernel(short* __restrict__ out, int n) {
    int i = blockIdx.x * 256 + threadIdx.x;
    if (i < n) out[i] = 0;
}

extern "C" void kernel_launch(void* const* d_in, const int* in_sizes, int n_in,
                              void* d_out, int out_size, void* d_ws, size_t ws_size,
                              hipStream_t stream) {
    const void* token = d_in[0];
    const void* Wp[3] = { d_in[1], d_in[2], d_in[3] };
    {
        int wi = 0;
        const void* tk = nullptr; const void* ws3[3] = {nullptr, nullptr, nullptr};
        bool ok = true;
        for (int i = 0; i < n_in && i < 4; ++i) {
            if (in_sizes[i] == BDIM * SDIM * DDIM) { if (tk) ok = false; tk = d_in[i]; }
            else if (in_sizes[i] == DDIM * DDIM) { if (wi < 3) ws3[wi++] = d_in[i]; else ok = false; }
            else ok = false;
        }
        if (ok && tk && wi == 3) { token = tk; Wp[0] = ws3[0]; Wp[1] = ws3[1]; Wp[2] = ws3[2]; }
    }

    const size_t qkvBytes = 3 * (size_t)MROWS * DDIM * sizeof(short);  // 48 MB
    const size_t need_base = qkvBytes + 256;
    if (ws_size < need_base) {
        zero_out_kernel<<<(out_size + 255) / 256, 256, 0, stream>>>((short*)d_out, out_size);
        return;
    }

    short* QKV = (short*)d_ws;
    int* flag = (int*)((char*)d_ws + qkvBytes);
    short* P = (short*)((char*)d_ws + need_base);   // P slab; Xb/Wb overlap (dead before qkt)
    const size_t pElems1 = (size_t)SDIM * SDIM;

    int nb = 0;
    for (int cand = 4; cand >= 1; cand >>= 1) {
        const size_t need = need_base + (size_t)cand * pElems1 * sizeof(short)
                          + (size_t)MROWS * sizeof(float);
        if (ws_size >= need) { nb = cand; break; }
    }

    detect_kernel<<<1, 256, 0, stream>>>((const uint32_t*)token, flag);

    if (nb == 0) {
        proj_mfma_legacy<<<dim3(1536), 256, 0, stream>>>(token, Wp[0], Wp[1], Wp[2], QKV, flag);
        attn_mfma<<<dim3(512), 256, 0, stream>>>(QKV, d_out, flag);
        return;
    }

    // Xb|W1b|W2b|W3b live at the head of the P slab (18.35 MB <= 32 MB min slab).
    short* XbWb = P;
    const size_t cvt4 = (XB_ELEMS + 3 * W_ELEMS) / 4;  // 2293760 lanes
    convert_kernel<<<dim3((unsigned)(cvt4 / 256)), 256, 0, stream>>>(
        token, Wp[0], Wp[1], Wp[2], XbWb, flag);
    proj_fast<<<dim3(1536), 256, 0, stream>>>(XbWb, QKV);

    float* RS = (float*)(P + (size_t)nb * pElems1);
    zero_rs_kernel<<<dim3(MROWS / 256), 256, 0, stream>>>(RS);
    for (int p = 0; p < BDIM / nb; ++p) {
        const int bbase = p * nb;
        qkt_kernel<<<dim3(nb * 512), 512, 0, stream>>>(QKV, P, RS, bbase);
        pv_kernel<<<dim3(nb * 64), 512, 0, stream>>>(P, QKV, RS, d_out, flag, bbase);
    }
}

// Round 4
// 373.885 us; speedup vs baseline: 1.0324x; 1.0324x over previous
//
#include <hip/hip_runtime.h>
#include <stdint.h>

// ContextAttention: B=4, S=4096, D=512.
// Round 13: revert to r9 geometry (128x128 @256thr, proven 354us), change ONLY
// the K-loop: minimum 2-phase double-buffer (catalog T3 short form, m248).
// STAGE(next) issued BEFORE ds_read+MFMA(cur); ONE __syncthreads per K-step
// (implicit vmcnt(0)+lgkmcnt(0) drain = required fence). Load latency hides
// under compute; barriers halve. LDS 32KB (2 bufs), regs unchanged (<=128 cap).
// r12's 256x128 wide tile REFUTED (147us vs 120): fewer blocks + lockstep
// 8-wave barriers beat the staged-bytes saving.
// BANNED: __launch_bounds__ (crash-assoc rounds 1-3). All grids 1-D.

#define BDIM 4
#define SDIM 4096
#define DDIM 512
#define MROWS (BDIM * SDIM)  // 16384
#define XB_ELEMS ((size_t)MROWS * DDIM)        // 8388608
#define W_ELEMS ((size_t)DDIM * DDIM)          // 262144

typedef short short8_t __attribute__((ext_vector_type(8)));
typedef short short4_t __attribute__((ext_vector_type(4)));
typedef float float4_t __attribute__((ext_vector_type(4)));

typedef __attribute__((address_space(1))) void gvoid_t;
typedef __attribute__((address_space(3))) void lvoid_t;

__device__ __forceinline__ short f2bf(float f) {
    union { float f; uint32_t u; } v; v.f = f;
    uint32_t r = v.u + 0x7FFFu + ((v.u >> 16) & 1u);  // RNE
    return (short)(r >> 16);
}
__device__ __forceinline__ float bf2f(short s) {
    union { uint32_t u; float f; } v; v.u = ((uint32_t)(uint16_t)s) << 16;
    return v.f;
}

// Storage-dtype vote (proven).
__global__ void detect_kernel(const uint32_t* __restrict__ tok, int* __restrict__ flag) {
    __shared__ int red[256];
    const int tid = threadIdx.x;
    int c = 0;
    for (int i = tid; i < 4096; i += 256) {
        uint32_t e = (tok[i] >> 7) & 0xFFu;
        c += (e >= 105u && e <= 135u) ? 1 : 0;
    }
    red[tid] = c;
    __syncthreads();
    for (int s = 128; s > 0; s >>= 1) {
        if (tid < s) red[tid] += red[tid + s];
        __syncthreads();
    }
    if (tid == 0) *flag = (red[0] > 2048) ? 1 : 0;  // 1 = bf16 storage
}

__global__ void zero_rs_kernel(float* __restrict__ RS) {
    RS[blockIdx.x * 256 + threadIdx.x] = 0.f;
}

// Pre-convert inputs to bf16: dst = Xb[8388608] | W1b | W2b | W3b (262144 ea).
__global__ void convert_kernel(const void* __restrict__ X, const void* __restrict__ W1,
                               const void* __restrict__ W2, const void* __restrict__ W3,
                               short* __restrict__ dst, const int* __restrict__ flagp)
{
    const int bf16in = *flagp;
    const size_t i4 = ((size_t)blockIdx.x * 256 + threadIdx.x) * 4;  // elem index
    const void* src; size_t off;
    if (i4 < XB_ELEMS) { src = X; off = i4; }
    else {
        const size_t j = i4 - XB_ELEMS;
        const int g = (int)(j / W_ELEMS);
        src = (g == 0) ? W1 : (g == 1) ? W2 : W3;
        off = j - (size_t)g * W_ELEMS;
    }
    if (bf16in) {
        *(short4_t*)(dst + i4) = *(const short4_t*)((const short*)src + off);
    } else {
        float4 v = *(const float4*)((const float*)src + off);
        short4_t s = { f2bf(v.x), f2bf(v.y), f2bf(v.z), f2bf(v.w) };
        *(short4_t*)(dst + i4) = s;
    }
}

// ------- m97-style GEMM core, 128x128 @256thr, BK=32, double-buffered -------
// LDS: As/Bs each 2 x [128][32] (unpadded; global_load_lds w16 staging).
// K-loop: STAGE(next buf) issued BEFORE ds_read+MFMA(cur buf); single
// __syncthreads per step (implicit vmcnt(0)+lgkmcnt(0) drain fences both the
// landed next tile and the consumed current tile). Load latency hides under
// the 16 MFMA + 8 ds_read of the current step.
__device__ __forceinline__ void gemm_core(
    const short* __restrict__ A, int lda,
    const short* __restrict__ B, int ldb,
    int m0, int n0, int kIters,
    short* As, short* Bs, float4_t acc[4][4])
{
    const int tid = threadIdx.x;
    const int w = tid >> 6, lane = tid & 63, quad = lane >> 4, l16 = lane & 15;
    const int wm = w >> 1, wn = w & 1;
    const int rsub = lane >> 2;          // row within 16-row chunk
    const int col8 = 8 * (lane & 3);     // 8-elem (16B) column chunk

    auto STAGE = [&](int d, int kk) {
        const int k0 = 32 * kk;
        short* Asd = As + d * 4096;
        short* Bsd = Bs + d * 4096;
#pragma unroll
        for (int c = 0; c < 2; ++c) {
            const int row = 32 * w + 16 * c + rsub;
            const short* g = A + (size_t)(m0 + row) * lda + k0 + col8;
            __builtin_amdgcn_global_load_lds((const gvoid_t*)g,
                (lvoid_t*)(Asd + (32 * w + 16 * c) * 32), 16, 0, 0);
        }
#pragma unroll
        for (int c = 0; c < 2; ++c) {
            const int row = 32 * w + 16 * c + rsub;
            const short* g = B + (size_t)(n0 + row) * ldb + k0 + col8;
            __builtin_amdgcn_global_load_lds((const gvoid_t*)g,
                (lvoid_t*)(Bsd + (32 * w + 16 * c) * 32), 16, 0, 0);
        }
    };

    STAGE(0, 0);
    __syncthreads();                       // tile 0 landed
    int cur = 0;
    for (int kk = 0; kk < kIters; ++kk) {
        if (kk + 1 < kIters) STAGE(cur ^ 1, kk + 1);   // overlap with compute
        const short* Asd = As + cur * 4096;
        const short* Bsd = Bs + cur * 4096;
        short8_t af[4], bfr[4];
#pragma unroll
        for (int mt = 0; mt < 4; ++mt)
            af[mt] = *(const short8_t*)&Asd[(64 * wm + 16 * mt + l16) * 32 + 8 * quad];
#pragma unroll
        for (int nt = 0; nt < 4; ++nt)
            bfr[nt] = *(const short8_t*)&Bsd[(64 * wn + 16 * nt + l16) * 32 + 8 * quad];
#pragma unroll
        for (int mt = 0; mt < 4; ++mt)
#pragma unroll
            for (int nt = 0; nt < 4; ++nt)
                acc[mt][nt] = __builtin_amdgcn_mfma_f32_16x16x32_bf16(af[mt], bfr[nt], acc[mt][nt], 0, 0, 0);
        __syncthreads();                   // next tile landed; cur consumed
        cur ^= 1;
    }
}

// ---------------- proj (all-bf16 via Xb/Wb) ----------------
// g=0: Q = Xb @ W1b^T; g=1: K; g=2: Vt[m=e][n=bs] = W3b @ Xb^T.
__global__ void proj_fast(const short* __restrict__ XbWb, short* __restrict__ QKV)
{
    __shared__ __align__(16) short As[2 * 128 * 32];
    __shared__ __align__(16) short Bs[2 * 128 * 32];

    const short* Xb = XbWb;
    const int bid = blockIdx.x;
    const int g = bid >> 9;
    const int r = bid & 511;

    const short* Ap; const short* Bp; short* Op;
    int m0, n0, ldo;
    if (g == 2) {
        Ap = XbWb + XB_ELEMS + 2 * W_ELEMS; Bp = Xb;
        Op = QKV + 2 * (size_t)MROWS * DDIM;
        m0 = 128 * (r & 3); n0 = 128 * (r >> 2); ldo = MROWS;   // Vt[e][bs]
    } else {
        Ap = Xb; Bp = XbWb + XB_ELEMS + (size_t)g * W_ELEMS;
        Op = QKV + (size_t)g * MROWS * DDIM;
        m0 = 128 * (r >> 2); n0 = 128 * (r & 3); ldo = DDIM;    // Q/K[bs][e]
    }

    const float4_t z4 = {0.f, 0.f, 0.f, 0.f};
    float4_t acc[4][4];
#pragma unroll
    for (int i = 0; i < 4; ++i)
#pragma unroll
        for (int j = 0; j < 4; ++j) acc[i][j] = z4;

    gemm_core(Ap, DDIM, Bp, DDIM, m0, n0, 16, As, Bs, acc);

    const int tid = threadIdx.x;
    const int w = tid >> 6, lane = tid & 63, quad = lane >> 4, l16 = lane & 15;
    const int wm = w >> 1, wn = w & 1;
#pragma unroll
    for (int mt = 0; mt < 4; ++mt)
#pragma unroll
        for (int nt = 0; nt < 4; ++nt)
#pragma unroll
            for (int rr = 0; rr < 4; ++rr) {
                const int m = m0 + 64 * wm + 16 * mt + 4 * quad + rr;
                const int n = n0 + 64 * wn + 16 * nt + l16;
                Op[(size_t)m * ldo + n] = f2bf(acc[mt][nt][rr]);
            }
}

// ---------------- qkt: P = exp(sc * Q K^T) + rowsums ----------------
__global__ void qkt_kernel(const short* __restrict__ QKV, short* __restrict__ P,
                           float* __restrict__ RS, int bbase)
{
    __shared__ __align__(16) short As[2 * 128 * 32];
    __shared__ __align__(16) short Bs[2 * 128 * 32];

    const int bid = blockIdx.x;
    const int bb = bid >> 10;
    const int r = bid & 1023;
    const int b = bbase + bb;
    const int m0 = 128 * (r >> 5);
    const int n0 = 128 * (r & 31);

    const short* Qb = QKV + (size_t)b * SDIM * DDIM;
    const short* Kb = QKV + (size_t)MROWS * DDIM + (size_t)b * SDIM * DDIM;

    const float4_t z4 = {0.f, 0.f, 0.f, 0.f};
    float4_t acc[4][4];
#pragma unroll
    for (int i = 0; i < 4; ++i)
#pragma unroll
        for (int j = 0; j < 4; ++j) acc[i][j] = z4;

    gemm_core(Qb, DDIM, Kb, DDIM, m0, n0, 16, As, Bs, acc);

    const int tid = threadIdx.x;
    const int w = tid >> 6, lane = tid & 63, quad = lane >> 4, l16 = lane & 15;
    const int wm = w >> 1, wn = w & 1;
    const float kSc = 1.44269504088896341f * 0.04419417382415922f;  // log2(e)/sqrt(512)
    short* Pb = P + (size_t)bb * SDIM * SDIM;
#pragma unroll
    for (int mt = 0; mt < 4; ++mt)
#pragma unroll
        for (int rr = 0; rr < 4; ++rr) {
            const int q = m0 + 64 * wm + 16 * mt + 4 * quad + rr;
            float sum = 0.f;
#pragma unroll
            for (int nt = 0; nt < 4; ++nt) {
                const float p = exp2f(acc[mt][nt][rr] * kSc);
                const short pb = f2bf(p);
                sum += bf2f(pb);
                Pb[(size_t)q * SDIM + n0 + 64 * wn + 16 * nt + l16] = pb;
            }
            sum += __shfl_xor(sum, 1); sum += __shfl_xor(sum, 2);
            sum += __shfl_xor(sum, 4); sum += __shfl_xor(sum, 8);
            if (l16 == 0) atomicAdd(&RS[(size_t)b * SDIM + q], sum);
        }
}

// ---------------- pv: out = (P @ Vt-rows) / RS ----------------
__global__ void pv_kernel(const short* __restrict__ P, const short* __restrict__ QKV,
                          const float* __restrict__ RS, void* __restrict__ out,
                          const int* __restrict__ flagp, int bbase)
{
    __shared__ __align__(16) short As[2 * 128 * 32];
    __shared__ __align__(16) short Bs[2 * 128 * 32];

    const int bf16out = *flagp;
    const int bid = blockIdx.x;
    const int bb = bid >> 7;
    const int r = bid & 127;
    const int b = bbase + bb;
    const int m0 = 128 * (r >> 2);
    const int n0 = 128 * (r & 3);

    const short* Pb = P + (size_t)bb * SDIM * SDIM;
    const short* Vt = QKV + 2 * (size_t)MROWS * DDIM + (size_t)b * SDIM;  // rows stride MROWS

    const float4_t z4 = {0.f, 0.f, 0.f, 0.f};
    float4_t acc[4][4];
#pragma unroll
    for (int i = 0; i < 4; ++i)
#pragma unroll
        for (int j = 0; j < 4; ++j) acc[i][j] = z4;

    gemm_core(Pb, SDIM, Vt, MROWS, m0, n0, 128, As, Bs, acc);

    const int tid = threadIdx.x;
    const int w = tid >> 6, lane = tid & 63, quad = lane >> 4, l16 = lane & 15;
    const int wm = w >> 1, wn = w & 1;
#pragma unroll
    for (int mt = 0; mt < 4; ++mt)
#pragma unroll
        for (int rr = 0; rr < 4; ++rr) {
            const size_t grow = (size_t)b * SDIM + m0 + 64 * wm + 16 * mt + 4 * quad + rr;
            const float inv = 1.0f / RS[grow];
#pragma unroll
            for (int nt = 0; nt < 4; ++nt) {
                const int n = n0 + 64 * wn + 16 * nt + l16;
                const float o = acc[mt][nt][rr] * inv;
                if (bf16out) ((short*)out)[grow * DDIM + n] = f2bf(o);
                else         ((float*)out)[grow * DDIM + n] = o;
            }
        }
}

// ---------------- Fallbacks (proven round-6/8 versions) ----------------
__global__ void proj_mfma_legacy(const void* __restrict__ X, const void* __restrict__ W1,
                          const void* __restrict__ W2, const void* __restrict__ W3,
                          short* __restrict__ QKV, const int* __restrict__ flagp)
{
    __shared__ __align__(16) short As[128][40];
    __shared__ __align__(16) short Bs[128][40];

    const int bf16in = *flagp;
    const int bid = blockIdx.x;
    const int g = bid >> 9;
    const int r = bid & 511;

    const void* Ap; const void* Bp; short* Op;
    int m0, n0, ldo;
    if (g == 2) {
        Ap = W3; Bp = X; Op = QKV + 2 * (size_t)MROWS * DDIM;
        m0 = 128 * (r & 3); n0 = 128 * (r >> 2); ldo = MROWS;
    } else {
        Ap = X; Bp = (g == 0) ? W1 : W2; Op = QKV + (size_t)g * MROWS * DDIM;
        m0 = 128 * (r >> 2); n0 = 128 * (r & 3); ldo = DDIM;
    }

    const float* Af = (const float*)Ap;  const float* Bf = (const float*)Bp;
    const short* Ah = (const short*)Ap;  const short* Bh = (const short*)Bp;

    const int tid = threadIdx.x;
    const int w = tid >> 6, lane = tid & 63, quad = lane >> 4, l16 = lane & 15;
    const int wm = w >> 1, wn = w & 1;
    const int rgrp = tid >> 3, cg = tid & 7;

    const float4_t z4 = {0.f, 0.f, 0.f, 0.f};
    float4_t acc[4][4];
#pragma unroll
    for (int i = 0; i < 4; ++i)
#pragma unroll
        for (int j = 0; j < 4; ++j) acc[i][j] = z4;

    for (int kk = 0; kk < 16; ++kk) {
        const int k0 = 32 * kk;
        __syncthreads();
        if (bf16in) {
#pragma unroll
            for (int i = 0; i < 4; ++i) {
                const int row = rgrp + 32 * i;
                *(short4_t*)&As[row][4 * cg] =
                    *(const short4_t*)(Ah + (size_t)(m0 + row) * DDIM + k0 + 4 * cg);
                *(short4_t*)&Bs[row][4 * cg] =
                    *(const short4_t*)(Bh + (size_t)(n0 + row) * DDIM + k0 + 4 * cg);
            }
        } else {
#pragma unroll
            for (int i = 0; i < 4; ++i) {
                const int row = rgrp + 32 * i;
                float4 va = *(const float4*)(Af + (size_t)(m0 + row) * DDIM + k0 + 4 * cg);
                short4_t sa = { f2bf(va.x), f2bf(va.y), f2bf(va.z), f2bf(va.w) };
                *(short4_t*)&As[row][4 * cg] = sa;
                float4 vb = *(const float4*)(Bf + (size_t)(n0 + row) * DDIM + k0 + 4 * cg);
                short4_t sb = { f2bf(vb.x), f2bf(vb.y), f2bf(vb.z), f2bf(vb.w) };
                *(short4_t*)&Bs[row][4 * cg] = sb;
            }
        }
        __syncthreads();

        short8_t af[4], bfr[4];
#pragma unroll
        for (int mt = 0; mt < 4; ++mt)
            af[mt] = *(const short8_t*)&As[64 * wm + 16 * mt + l16][8 * quad];
#pragma unroll
        for (int nt = 0; nt < 4; ++nt)
            bfr[nt] = *(const short8_t*)&Bs[64 * wn + 16 * nt + l16][8 * quad];
#pragma unroll
        for (int mt = 0; mt < 4; ++mt)
#pragma unroll
            for (int nt = 0; nt < 4; ++nt)
                acc[mt][nt] = __builtin_amdgcn_mfma_f32_16x16x32_bf16(af[mt], bfr[nt], acc[mt][nt], 0, 0, 0);
    }

#pragma unroll
    for (int mt = 0; mt < 4; ++mt)
#pragma unroll
        for (int nt = 0; nt < 4; ++nt)
#pragma unroll
            for (int rr = 0; rr < 4; ++rr) {
                const int m = m0 + 64 * wm + 16 * mt + 4 * quad + rr;
                const int n = n0 + 64 * wn + 16 * nt + l16;
                Op[(size_t)m * ldo + n] = f2bf(acc[mt][nt][rr]);
            }
}

__global__ void attn_mfma(const short* __restrict__ QKV, void* __restrict__ out,
                          const int* __restrict__ flagp)
{
    __shared__ __align__(16) short Ks[32][520];
    __shared__ __align__(16) short Ps[32][72];
    __shared__ float rowsum[2][32];

    const int bf16out = *flagp;
    const short* Qb = QKV;
    const short* Kb = QKV + (size_t)MROWS * DDIM;
    const short* Vt = QKV + 2 * (size_t)MROWS * DDIM;

    const int b = blockIdx.x >> 7;
    const int q0 = (blockIdx.x & 127) * 32;
    const int tid = threadIdx.x;
    const int w = tid >> 6, lane = tid & 63, quad = lane >> 4, l16 = lane & 15;
    const int strip = w >> 1, half = w & 1;

    short8_t qf[16];
    {
        const short* qrow = Qb + (size_t)(b * SDIM + q0 + 16 * strip + l16) * DDIM + 8 * quad;
#pragma unroll
        for (int kc = 0; kc < 16; ++kc)
            qf[kc] = *(const short8_t*)(qrow + 32 * kc);
    }

    const float4_t z4 = {0.f, 0.f, 0.f, 0.f};
    float4_t o[2][8];
#pragma unroll
    for (int mt = 0; mt < 2; ++mt)
#pragma unroll
        for (int nt = 0; nt < 8; ++nt) o[mt][nt] = z4;
    float rs[4] = {0.f, 0.f, 0.f, 0.f};

    const float kSc = 1.44269504088896341f * 0.04419417382415922f;

    for (int kt = 0; kt < 128; ++kt) {
        const int kv0 = 32 * kt;
        __syncthreads();
#pragma unroll
        for (int r = 0; r < 8; ++r) {
            const int kv = 8 * w + r;
            short8_t t = *(const short8_t*)(Kb + (size_t)(b * SDIM + kv0 + kv) * DDIM + 8 * lane);
            *(short8_t*)&Ks[kv][8 * lane] = t;
        }
        __syncthreads();

        float4_t sacc = z4;
#pragma unroll
        for (int kc = 0; kc < 16; ++kc) {
            short8_t kf = *(const short8_t*)&Ks[16 * half + l16][32 * kc + 8 * quad];
            sacc = __builtin_amdgcn_mfma_f32_16x16x32_bf16(qf[kc], kf, sacc, 0, 0, 0);
        }

#pragma unroll
        for (int r = 0; r < 4; ++r) {
            const float p = exp2f(sacc[r] * kSc);
            const short pb = f2bf(p);
            rs[r] += bf2f(pb);
            Ps[16 * strip + 4 * quad + r][16 * half + l16] = pb;
        }
        __syncthreads();

        short8_t pa0 = *(const short8_t*)&Ps[l16][8 * quad];
        short8_t pa1 = *(const short8_t*)&Ps[16 + l16][8 * quad];
#pragma unroll
        for (int nt = 0; nt < 8; ++nt) {
            const short* vp = Vt + (size_t)(128 * w + 16 * nt + l16) * MROWS
                            + (b * SDIM + kv0 + 8 * quad);
            short8_t vb = *(const short8_t*)vp;
            o[0][nt] = __builtin_amdgcn_mfma_f32_16x16x32_bf16(pa0, vb, o[0][nt], 0, 0, 0);
            o[1][nt] = __builtin_amdgcn_mfma_f32_16x16x32_bf16(pa1, vb, o[1][nt], 0, 0, 0);
        }
    }

#pragma unroll
    for (int r = 0; r < 4; ++r) {
        float v = rs[r];
        v += __shfl_xor(v, 1); v += __shfl_xor(v, 2);
        v += __shfl_xor(v, 4); v += __shfl_xor(v, 8);
        rs[r] = v;
    }
    if (l16 == 0) {
#pragma unroll
        for (int r = 0; r < 4; ++r)
            rowsum[half][16 * strip + 4 * quad + r] = rs[r];
    }
    __syncthreads();

#pragma unroll
    for (int mt = 0; mt < 2; ++mt)
#pragma unroll
        for (int r = 0; r < 4; ++r) {
            const int q = 16 * mt + 4 * quad + r;
            const float inv = 1.0f / (rowsum[0][q] + rowsum[1][q]);
            const size_t base = (size_t)(b * SDIM + q0 + q) * DDIM + 128 * w + l16;
            if (bf16out) {
                short* orow = (short*)out + base;
#pragma unroll
                for (int nt = 0; nt < 8; ++nt)
                    orow[16 * nt] = f2bf(o[mt][nt][r] * inv);
            } else {
                float* orow = (float*)out + base;
#pragma unroll
                for (int nt = 0; nt < 8; ++nt)
                    orow[16 * nt] = o[mt][nt][r] * inv;
            }
        }
}

__global__ void zero_out_kernel(short* __restrict__ out, int n) {
    int i = blockIdx.x * 256 + threadIdx.x;
    if (i < n) out[i] = 0;
}

extern "C" void kernel_launch(void* const* d_in, const int* in_sizes, int n_in,
                              void* d_out, int out_size, void* d_ws, size_t ws_size,
                              hipStream_t stream) {
    const void* token = d_in[0];
    const void* Wp[3] = { d_in[1], d_in[2], d_in[3] };
    {
        int wi = 0;
        const void* tk = nullptr; const void* ws3[3] = {nullptr, nullptr, nullptr};
        bool ok = true;
        for (int i = 0; i < n_in && i < 4; ++i) {
            if (in_sizes[i] == BDIM * SDIM * DDIM) { if (tk) ok = false; tk = d_in[i]; }
            else if (in_sizes[i] == DDIM * DDIM) { if (wi < 3) ws3[wi++] = d_in[i]; else ok = false; }
            else ok = false;
        }
        if (ok && tk && wi == 3) { token = tk; Wp[0] = ws3[0]; Wp[1] = ws3[1]; Wp[2] = ws3[2]; }
    }

    const size_t qkvBytes = 3 * (size_t)MROWS * DDIM * sizeof(short);  // 48 MB
    const size_t need_base = qkvBytes + 256;
    if (ws_size < need_base) {
        zero_out_kernel<<<(out_size + 255) / 256, 256, 0, stream>>>((short*)d_out, out_size);
        return;
    }

    short* QKV = (short*)d_ws;
    int* flag = (int*)((char*)d_ws + qkvBytes);
    short* P = (short*)((char*)d_ws + need_base);   // P slab; Xb/Wb overlap (dead before qkt)
    const size_t pElems1 = (size_t)SDIM * SDIM;

    int nb = 0;
    for (int cand = 4; cand >= 1; cand >>= 1) {
        const size_t need = need_base + (size_t)cand * pElems1 * sizeof(short)
                          + (size_t)MROWS * sizeof(float);
        if (ws_size >= need) { nb = cand; break; }
    }

    detect_kernel<<<1, 256, 0, stream>>>((const uint32_t*)token, flag);

    if (nb == 0) {
        proj_mfma_legacy<<<dim3(1536), 256, 0, stream>>>(token, Wp[0], Wp[1], Wp[2], QKV, flag);
        attn_mfma<<<dim3(512), 256, 0, stream>>>(QKV, d_out, flag);
        return;
    }

    // Xb|W1b|W2b|W3b live at the head of the P slab (18.35 MB <= 32 MB min slab).
    short* XbWb = P;
    const size_t cvt4 = (XB_ELEMS + 3 * W_ELEMS) / 4;  // 2293760 lanes
    convert_kernel<<<dim3((unsigned)(cvt4 / 256)), 256, 0, stream>>>(
        token, Wp[0], Wp[1], Wp[2], XbWb, flag);
    proj_fast<<<dim3(1536), 256, 0, stream>>>(XbWb, QKV);

    float* RS = (float*)(P + (size_t)nb * pElems1);
    zero_rs_kernel<<<dim3(MROWS / 256), 256, 0, stream>>>(RS);
    for (int p = 0; p < BDIM / nb; ++p) {
        const int bbase = p * nb;
        qkt_kernel<<<dim3(nb * 1024), 256, 0, stream>>>(QKV, P, RS, bbase);
        pv_kernel<<<dim3(nb * 128), 256, 0, stream>>>(P, QKV, RS, d_out, flag, bbase);
    }
}

// Round 5
// 348.062 us; speedup vs baseline: 1.1089x; 1.0742x over previous
//
#include <hip/hip_runtime.h>
#include <stdint.h>

// ContextAttention: B=4, S=4096, D=512.
// Round 14: EXACT r9 kernel (best proven, 354us: single-buffer m97 core,
// 128x128 @256thr, 2 barriers/K-step) + ONE isolated change: XCD-chunked
// bijective swizzle (T1) on qkt & pv grids. Mechanism: panel-sharing
// neighbor blocks (pv: 4 blocks/P-panel; qkt: 32 blocks/Q-panel + 4MB K slab)
// land on the SAME XCD -> L2-resident panels, cut L3/HBM re-fetch.
// K-loop restructuring is DEAD under the 128-reg cap (r10-r13 all null/neg).
// BANNED: __launch_bounds__ (crash-assoc rounds 1-3). All grids 1-D.

#define BDIM 4
#define SDIM 4096
#define DDIM 512
#define MROWS (BDIM * SDIM)  // 16384
#define XB_ELEMS ((size_t)MROWS * DDIM)        // 8388608
#define W_ELEMS ((size_t)DDIM * DDIM)          // 262144

typedef short short8_t __attribute__((ext_vector_type(8)));
typedef short short4_t __attribute__((ext_vector_type(4)));
typedef float float4_t __attribute__((ext_vector_type(4)));

typedef __attribute__((address_space(1))) void gvoid_t;
typedef __attribute__((address_space(3))) void lvoid_t;

__device__ __forceinline__ short f2bf(float f) {
    union { float f; uint32_t u; } v; v.f = f;
    uint32_t r = v.u + 0x7FFFu + ((v.u >> 16) & 1u);  // RNE
    return (short)(r >> 16);
}
__device__ __forceinline__ float bf2f(short s) {
    union { uint32_t u; float f; } v; v.u = ((uint32_t)(uint16_t)s) << 16;
    return v.f;
}

// Storage-dtype vote (proven).
__global__ void detect_kernel(const uint32_t* __restrict__ tok, int* __restrict__ flag) {
    __shared__ int red[256];
    const int tid = threadIdx.x;
    int c = 0;
    for (int i = tid; i < 4096; i += 256) {
        uint32_t e = (tok[i] >> 7) & 0xFFu;
        c += (e >= 105u && e <= 135u) ? 1 : 0;
    }
    red[tid] = c;
    __syncthreads();
    for (int s = 128; s > 0; s >>= 1) {
        if (tid < s) red[tid] += red[tid + s];
        __syncthreads();
    }
    if (tid == 0) *flag = (red[0] > 2048) ? 1 : 0;  // 1 = bf16 storage
}

__global__ void zero_rs_kernel(float* __restrict__ RS) {
    RS[blockIdx.x * 256 + threadIdx.x] = 0.f;
}

// Pre-convert inputs to bf16: dst = Xb[8388608] | W1b | W2b | W3b (262144 ea).
__global__ void convert_kernel(const void* __restrict__ X, const void* __restrict__ W1,
                               const void* __restrict__ W2, const void* __restrict__ W3,
                               short* __restrict__ dst, const int* __restrict__ flagp)
{
    const int bf16in = *flagp;
    const size_t i4 = ((size_t)blockIdx.x * 256 + threadIdx.x) * 4;  // elem index
    const void* src; size_t off;
    if (i4 < XB_ELEMS) { src = X; off = i4; }
    else {
        const size_t j = i4 - XB_ELEMS;
        const int g = (int)(j / W_ELEMS);
        src = (g == 0) ? W1 : (g == 1) ? W2 : W3;
        off = j - (size_t)g * W_ELEMS;
    }
    if (bf16in) {
        *(short4_t*)(dst + i4) = *(const short4_t*)((const short*)src + off);
    } else {
        float4 v = *(const float4*)((const float*)src + off);
        short4_t s = { f2bf(v.x), f2bf(v.y), f2bf(v.z), f2bf(v.w) };
        *(short4_t*)(dst + i4) = s;
    }
}

// ---------------- shared m97-style GEMM core ----------------
// 128x128 tile, BK=32, unpadded LDS [128][32], staged via global_load_lds
// width=16 (wave-uniform LDS base + lane*16 == row-major 16-row chunk).
__device__ __forceinline__ void gemm_core(
    const short* __restrict__ A, int lda,
    const short* __restrict__ B, int ldb,
    int m0, int n0, int kIters,
    short* As, short* Bs, float4_t acc[4][4])
{
    const int tid = threadIdx.x;
    const int w = tid >> 6, lane = tid & 63, quad = lane >> 4, l16 = lane & 15;
    const int wm = w >> 1, wn = w & 1;
    const int rsub = lane >> 2;          // row within 16-row chunk
    const int col8 = 8 * (lane & 3);     // 8-elem (16B) column chunk

    for (int kk = 0; kk < kIters; ++kk) {
        const int k0 = 32 * kk;
        __syncthreads();
#pragma unroll
        for (int c = 0; c < 2; ++c) {
            const int row = 32 * w + 16 * c + rsub;
            const short* g = A + (size_t)(m0 + row) * lda + k0 + col8;
            __builtin_amdgcn_global_load_lds((const gvoid_t*)g,
                (lvoid_t*)(As + (32 * w + 16 * c) * 32), 16, 0, 0);
        }
#pragma unroll
        for (int c = 0; c < 2; ++c) {
            const int row = 32 * w + 16 * c + rsub;
            const short* g = B + (size_t)(n0 + row) * ldb + k0 + col8;
            __builtin_amdgcn_global_load_lds((const gvoid_t*)g,
                (lvoid_t*)(Bs + (32 * w + 16 * c) * 32), 16, 0, 0);
        }
        __syncthreads();

        short8_t af[4], bfr[4];
#pragma unroll
        for (int mt = 0; mt < 4; ++mt)
            af[mt] = *(const short8_t*)&As[(64 * wm + 16 * mt + l16) * 32 + 8 * quad];
#pragma unroll
        for (int nt = 0; nt < 4; ++nt)
            bfr[nt] = *(const short8_t*)&Bs[(64 * wn + 16 * nt + l16) * 32 + 8 * quad];
#pragma unroll
        for (int mt = 0; mt < 4; ++mt)
#pragma unroll
            for (int nt = 0; nt < 4; ++nt)
                acc[mt][nt] = __builtin_amdgcn_mfma_f32_16x16x32_bf16(af[mt], bfr[nt], acc[mt][nt], 0, 0, 0);
    }
}

// ---------------- proj (all-bf16 via Xb/Wb) ----------------
// g=0: Q = Xb @ W1b^T; g=1: K; g=2: Vt[m=e][n=bs] = W3b @ Xb^T.
__global__ void proj_fast(const short* __restrict__ XbWb, short* __restrict__ QKV)
{
    __shared__ __align__(16) short As[128 * 32];
    __shared__ __align__(16) short Bs[128 * 32];

    const short* Xb = XbWb;
    const int bid = blockIdx.x;
    const int g = bid >> 9;
    const int r = bid & 511;

    const short* Ap; const short* Bp; short* Op;
    int m0, n0, ldo;
    if (g == 2) {
        Ap = XbWb + XB_ELEMS + 2 * W_ELEMS; Bp = Xb;
        Op = QKV + 2 * (size_t)MROWS * DDIM;
        m0 = 128 * (r & 3); n0 = 128 * (r >> 2); ldo = MROWS;   // Vt[e][bs]
    } else {
        Ap = Xb; Bp = XbWb + XB_ELEMS + (size_t)g * W_ELEMS;
        Op = QKV + (size_t)g * MROWS * DDIM;
        m0 = 128 * (r >> 2); n0 = 128 * (r & 3); ldo = DDIM;    // Q/K[bs][e]
    }

    const float4_t z4 = {0.f, 0.f, 0.f, 0.f};
    float4_t acc[4][4];
#pragma unroll
    for (int i = 0; i < 4; ++i)
#pragma unroll
        for (int j = 0; j < 4; ++j) acc[i][j] = z4;

    gemm_core(Ap, DDIM, Bp, DDIM, m0, n0, 16, As, Bs, acc);

    const int tid = threadIdx.x;
    const int w = tid >> 6, lane = tid & 63, quad = lane >> 4, l16 = lane & 15;
    const int wm = w >> 1, wn = w & 1;
#pragma unroll
    for (int mt = 0; mt < 4; ++mt)
#pragma unroll
        for (int nt = 0; nt < 4; ++nt)
#pragma unroll
            for (int rr = 0; rr < 4; ++rr) {
                const int m = m0 + 64 * wm + 16 * mt + 4 * quad + rr;
                const int n = n0 + 64 * wn + 16 * nt + l16;
                Op[(size_t)m * ldo + n] = f2bf(acc[mt][nt][rr]);
            }
}

// ---------------- qkt: P = exp(sc * Q K^T) + rowsums ----------------
// Grid nb*1024 (%8==0). XCD-chunked swizzle: XCD x gets a contiguous logical
// range -> 32-block Q-panel groups + the 4MB per-batch K slab stay in one L2.
__global__ void qkt_kernel(const short* __restrict__ QKV, short* __restrict__ P,
                           float* __restrict__ RS, int bbase)
{
    __shared__ __align__(16) short As[128 * 32];
    __shared__ __align__(16) short Bs[128 * 32];

    const int cpx = (int)(gridDim.x >> 3);          // grid % 8 == 0 (bijective)
    const int bid = (int)blockIdx.x;
    const int l = (bid & 7) * cpx + (bid >> 3);     // XCD chunk (T1)
    const int bb = l >> 10;
    const int r = l & 1023;
    const int b = bbase + bb;
    const int m0 = 128 * (r >> 5);
    const int n0 = 128 * (r & 31);

    const short* Qb = QKV + (size_t)b * SDIM * DDIM;
    const short* Kb = QKV + (size_t)MROWS * DDIM + (size_t)b * SDIM * DDIM;

    const float4_t z4 = {0.f, 0.f, 0.f, 0.f};
    float4_t acc[4][4];
#pragma unroll
    for (int i = 0; i < 4; ++i)
#pragma unroll
        for (int j = 0; j < 4; ++j) acc[i][j] = z4;

    gemm_core(Qb, DDIM, Kb, DDIM, m0, n0, 16, As, Bs, acc);

    const int tid = threadIdx.x;
    const int w = tid >> 6, lane = tid & 63, quad = lane >> 4, l16 = lane & 15;
    const int wm = w >> 1, wn = w & 1;
    const float kSc = 1.44269504088896341f * 0.04419417382415922f;  // log2(e)/sqrt(512)
    short* Pb = P + (size_t)bb * SDIM * SDIM;
#pragma unroll
    for (int mt = 0; mt < 4; ++mt)
#pragma unroll
        for (int rr = 0; rr < 4; ++rr) {
            const int q = m0 + 64 * wm + 16 * mt + 4 * quad + rr;
            float sum = 0.f;
#pragma unroll
            for (int nt = 0; nt < 4; ++nt) {
                const float p = exp2f(acc[mt][nt][rr] * kSc);
                const short pb = f2bf(p);
                sum += bf2f(pb);
                Pb[(size_t)q * SDIM + n0 + 64 * wn + 16 * nt + l16] = pb;
            }
            sum += __shfl_xor(sum, 1); sum += __shfl_xor(sum, 2);
            sum += __shfl_xor(sum, 4); sum += __shfl_xor(sum, 8);
            if (l16 == 0) atomicAdd(&RS[(size_t)b * SDIM + q], sum);
        }
}

// ---------------- pv: out = (P @ Vt-rows) / RS ----------------
// Grid nb*128 (%8==0). XCD-chunked swizzle: the 4 n-blocks sharing a P panel
// land on ONE XCD -> P fetched once into L2 (was 4x across XCDs); Vt slab
// (4MB/batch) L2-resident.
__global__ void pv_kernel(const short* __restrict__ P, const short* __restrict__ QKV,
                          const float* __restrict__ RS, void* __restrict__ out,
                          const int* __restrict__ flagp, int bbase)
{
    __shared__ __align__(16) short As[128 * 32];
    __shared__ __align__(16) short Bs[128 * 32];

    const int bf16out = *flagp;
    const int cpx = (int)(gridDim.x >> 3);          // grid % 8 == 0
    const int bid = (int)blockIdx.x;
    const int l = (bid & 7) * cpx + (bid >> 3);     // XCD chunk (T1)
    const int bb = l >> 7;
    const int r = l & 127;
    const int b = bbase + bb;
    const int m0 = 128 * (r >> 2);
    const int n0 = 128 * (r & 3);

    const short* Pb = P + (size_t)bb * SDIM * SDIM;
    const short* Vt = QKV + 2 * (size_t)MROWS * DDIM + (size_t)b * SDIM;  // rows stride MROWS

    const float4_t z4 = {0.f, 0.f, 0.f, 0.f};
    float4_t acc[4][4];
#pragma unroll
    for (int i = 0; i < 4; ++i)
#pragma unroll
        for (int j = 0; j < 4; ++j) acc[i][j] = z4;

    gemm_core(Pb, SDIM, Vt, MROWS, m0, n0, 128, As, Bs, acc);

    const int tid = threadIdx.x;
    const int w = tid >> 6, lane = tid & 63, quad = lane >> 4, l16 = lane & 15;
    const int wm = w >> 1, wn = w & 1;
#pragma unroll
    for (int mt = 0; mt < 4; ++mt)
#pragma unroll
        for (int rr = 0; rr < 4; ++rr) {
            const size_t grow = (size_t)b * SDIM + m0 + 64 * wm + 16 * mt + 4 * quad + rr;
            const float inv = 1.0f / RS[grow];
#pragma unroll
            for (int nt = 0; nt < 4; ++nt) {
                const int n = n0 + 64 * wn + 16 * nt + l16;
                const float o = acc[mt][nt][rr] * inv;
                if (bf16out) ((short*)out)[grow * DDIM + n] = f2bf(o);
                else         ((float*)out)[grow * DDIM + n] = o;
            }
        }
}

// ---------------- Fallbacks (proven round-6/8 versions) ----------------
__global__ void proj_mfma_legacy(const void* __restrict__ X, const void* __restrict__ W1,
                          const void* __restrict__ W2, const void* __restrict__ W3,
                          short* __restrict__ QKV, const int* __restrict__ flagp)
{
    __shared__ __align__(16) short As[128][40];
    __shared__ __align__(16) short Bs[128][40];

    const int bf16in = *flagp;
    const int bid = blockIdx.x;
    const int g = bid >> 9;
    const int r = bid & 511;

    const void* Ap; const void* Bp; short* Op;
    int m0, n0, ldo;
    if (g == 2) {
        Ap = W3; Bp = X; Op = QKV + 2 * (size_t)MROWS * DDIM;
        m0 = 128 * (r & 3); n0 = 128 * (r >> 2); ldo = MROWS;
    } else {
        Ap = X; Bp = (g == 0) ? W1 : W2; Op = QKV + (size_t)g * MROWS * DDIM;
        m0 = 128 * (r >> 2); n0 = 128 * (r & 3); ldo = DDIM;
    }

    const float* Af = (const float*)Ap;  const float* Bf = (const float*)Bp;
    const short* Ah = (const short*)Ap;  const short* Bh = (const short*)Bp;

    const int tid = threadIdx.x;
    const int w = tid >> 6, lane = tid & 63, quad = lane >> 4, l16 = lane & 15;
    const int wm = w >> 1, wn = w & 1;
    const int rgrp = tid >> 3, cg = tid & 7;

    const float4_t z4 = {0.f, 0.f, 0.f, 0.f};
    float4_t acc[4][4];
#pragma unroll
    for (int i = 0; i < 4; ++i)
#pragma unroll
        for (int j = 0; j < 4; ++j) acc[i][j] = z4;

    for (int kk = 0; kk < 16; ++kk) {
        const int k0 = 32 * kk;
        __syncthreads();
        if (bf16in) {
#pragma unroll
            for (int i = 0; i < 4; ++i) {
                const int row = rgrp + 32 * i;
                *(short4_t*)&As[row][4 * cg] =
                    *(const short4_t*)(Ah + (size_t)(m0 + row) * DDIM + k0 + 4 * cg);
                *(short4_t*)&Bs[row][4 * cg] =
                    *(const short4_t*)(Bh + (size_t)(n0 + row) * DDIM + k0 + 4 * cg);
            }
        } else {
#pragma unroll
            for (int i = 0; i < 4; ++i) {
                const int row = rgrp + 32 * i;
                float4 va = *(const float4*)(Af + (size_t)(m0 + row) * DDIM + k0 + 4 * cg);
                short4_t sa = { f2bf(va.x), f2bf(va.y), f2bf(va.z), f2bf(va.w) };
                *(short4_t*)&As[row][4 * cg] = sa;
                float4 vb = *(const float4*)(Bf + (size_t)(n0 + row) * DDIM + k0 + 4 * cg);
                short4_t sb = { f2bf(vb.x), f2bf(vb.y), f2bf(vb.z), f2bf(vb.w) };
                *(short4_t*)&Bs[row][4 * cg] = sb;
            }
        }
        __syncthreads();

        short8_t af[4], bfr[4];
#pragma unroll
        for (int mt = 0; mt < 4; ++mt)
            af[mt] = *(const short8_t*)&As[64 * wm + 16 * mt + l16][8 * quad];
#pragma unroll
        for (int nt = 0; nt < 4; ++nt)
            bfr[nt] = *(const short8_t*)&Bs[64 * wn + 16 * nt + l16][8 * quad];
#pragma unroll
        for (int mt = 0; mt < 4; ++mt)
#pragma unroll
            for (int nt = 0; nt < 4; ++nt)
                acc[mt][nt] = __builtin_amdgcn_mfma_f32_16x16x32_bf16(af[mt], bfr[nt], acc[mt][nt], 0, 0, 0);
    }

#pragma unroll
    for (int mt = 0; mt < 4; ++mt)
#pragma unroll
        for (int nt = 0; nt < 4; ++nt)
#pragma unroll
            for (int rr = 0; rr < 4; ++rr) {
                const int m = m0 + 64 * wm + 16 * mt + 4 * quad + rr;
                const int n = n0 + 64 * wn + 16 * nt + l16;
                Op[(size_t)m * ldo + n] = f2bf(acc[mt][nt][rr]);
            }
}

__global__ void attn_mfma(const short* __restrict__ QKV, void* __restrict__ out,
                          const int* __restrict__ flagp)
{
    __shared__ __align__(16) short Ks[32][520];
    __shared__ __align__(16) short Ps[32][72];
    __shared__ float rowsum[2][32];

    const int bf16out = *flagp;
    const short* Qb = QKV;
    const short* Kb = QKV + (size_t)MROWS * DDIM;
    const short* Vt = QKV + 2 * (size_t)MROWS * DDIM;

    const int b = blockIdx.x >> 7;
    const int q0 = (blockIdx.x & 127) * 32;
    const int tid = threadIdx.x;
    const int w = tid >> 6, lane = tid & 63, quad = lane >> 4, l16 = lane & 15;
    const int strip = w >> 1, half = w & 1;

    short8_t qf[16];
    {
        const short* qrow = Qb + (size_t)(b * SDIM + q0 + 16 * strip + l16) * DDIM + 8 * quad;
#pragma unroll
        for (int kc = 0; kc < 16; ++kc)
            qf[kc] = *(const short8_t*)(qrow + 32 * kc);
    }

    const float4_t z4 = {0.f, 0.f, 0.f, 0.f};
    float4_t o[2][8];
#pragma unroll
    for (int mt = 0; mt < 2; ++mt)
#pragma unroll
        for (int nt = 0; nt < 8; ++nt) o[mt][nt] = z4;
    float rs[4] = {0.f, 0.f, 0.f, 0.f};

    const float kSc = 1.44269504088896341f * 0.04419417382415922f;

    for (int kt = 0; kt < 128; ++kt) {
        const int kv0 = 32 * kt;
        __syncthreads();
#pragma unroll
        for (int r = 0; r < 8; ++r) {
            const int kv = 8 * w + r;
            short8_t t = *(const short8_t*)(Kb + (size_t)(b * SDIM + kv0 + kv) * DDIM + 8 * lane);
            *(short8_t*)&Ks[kv][8 * lane] = t;
        }
        __syncthreads();

        float4_t sacc = z4;
#pragma unroll
        for (int kc = 0; kc < 16; ++kc) {
            short8_t kf = *(const short8_t*)&Ks[16 * half + l16][32 * kc + 8 * quad];
            sacc = __builtin_amdgcn_mfma_f32_16x16x32_bf16(qf[kc], kf, sacc, 0, 0, 0);
        }

#pragma unroll
        for (int r = 0; r < 4; ++r) {
            const float p = exp2f(sacc[r] * kSc);
            const short pb = f2bf(p);
            rs[r] += bf2f(pb);
            Ps[16 * strip + 4 * quad + r][16 * half + l16] = pb;
        }
        __syncthreads();

        short8_t pa0 = *(const short8_t*)&Ps[l16][8 * quad];
        short8_t pa1 = *(const short8_t*)&Ps[16 + l16][8 * quad];
#pragma unroll
        for (int nt = 0; nt < 8; ++nt) {
            const short* vp = Vt + (size_t)(128 * w + 16 * nt + l16) * MROWS
                            + (b * SDIM + kv0 + 8 * quad);
            short8_t vb = *(const short8_t*)vp;
            o[0][nt] = __builtin_amdgcn_mfma_f32_16x16x32_bf16(pa0, vb, o[0][nt], 0, 0, 0);
            o[1][nt] = __builtin_amdgcn_mfma_f32_16x16x32_bf16(pa1, vb, o[1][nt], 0, 0, 0);
        }
    }

#pragma unroll
    for (int r = 0; r < 4; ++r) {
        float v = rs[r];
        v += __shfl_xor(v, 1); v += __shfl_xor(v, 2);
        v += __shfl_xor(v, 4); v += __shfl_xor(v, 8);
        rs[r] = v;
    }
    if (l16 == 0) {
#pragma unroll
        for (int r = 0; r < 4; ++r)
            rowsum[half][16 * strip + 4 * quad + r] = rs[r];
    }
    __syncthreads();

#pragma unroll
    for (int mt = 0; mt < 2; ++mt)
#pragma unroll
        for (int r = 0; r < 4; ++r) {
            const int q = 16 * mt + 4 * quad + r;
            const float inv = 1.0f / (rowsum[0][q] + rowsum[1][q]);
            const size_t base = (size_t)(b * SDIM + q0 + q) * DDIM + 128 * w + l16;
            if (bf16out) {
                short* orow = (short*)out + base;
#pragma unroll
                for (int nt = 0; nt < 8; ++nt)
                    orow[16 * nt] = f2bf(o[mt][nt][r] * inv);
            } else {
                float* orow = (float*)out + base;
#pragma unroll
                for (int nt = 0; nt < 8; ++nt)
                    orow[16 * nt] = o[mt][nt][r] * inv;
            }
        }
}

__global__ void zero_out_kernel(short* __restrict__ out, int n) {
    int i = blockIdx.x * 256 + threadIdx.x;
    if (i < n) out[i] = 0;
}

extern "C" void kernel_launch(void* const* d_in, const int* in_sizes, int n_in,
                              void* d_out, int out_size, void* d_ws, size_t ws_size,
                              hipStream_t stream) {
    const void* token = d_in[0];
    const void* Wp[3] = { d_in[1], d_in[2], d_in[3] };
    {
        int wi = 0;
        const void* tk = nullptr; const void* ws3[3] = {nullptr, nullptr, nullptr};
        bool ok = true;
        for (int i = 0; i < n_in && i < 4; ++i) {
            if (in_sizes[i] == BDIM * SDIM * DDIM) { if (tk) ok = false; tk = d_in[i]; }
            else if (in_sizes[i] == DDIM * DDIM) { if (wi < 3) ws3[wi++] = d_in[i]; else ok = false; }
            else ok = false;
        }
        if (ok && tk && wi == 3) { token = tk; Wp[0] = ws3[0]; Wp[1] = ws3[1]; Wp[2] = ws3[2]; }
    }

    const size_t qkvBytes = 3 * (size_t)MROWS * DDIM * sizeof(short);  // 48 MB
    const size_t need_base = qkvBytes + 256;
    if (ws_size < need_base) {
        zero_out_kernel<<<(out_size + 255) / 256, 256, 0, stream>>>((short*)d_out, out_size);
        return;
    }

    short* QKV = (short*)d_ws;
    int* flag = (int*)((char*)d_ws + qkvBytes);
    short* P = (short*)((char*)d_ws + need_base);   // P slab; Xb/Wb overlap (dead before qkt)
    const size_t pElems1 = (size_t)SDIM * SDIM;

    int nb = 0;
    for (int cand = 4; cand >= 1; cand >>= 1) {
        const size_t need = need_base + (size_t)cand * pElems1 * sizeof(short)
                          + (size_t)MROWS * sizeof(float);
        if (ws_size >= need) { nb = cand; break; }
    }

    detect_kernel<<<1, 256, 0, stream>>>((const uint32_t*)token, flag);

    if (nb == 0) {
        proj_mfma_legacy<<<dim3(1536), 256, 0, stream>>>(token, Wp[0], Wp[1], Wp[2], QKV, flag);
        attn_mfma<<<dim3(512), 256, 0, stream>>>(QKV, d_out, flag);
        return;
    }

    // Xb|W1b|W2b|W3b live at the head of the P slab (18.35 MB <= 32 MB min slab).
    short* XbWb = P;
    const size_t cvt4 = (XB_ELEMS + 3 * W_ELEMS) / 4;  // 2293760 lanes
    convert_kernel<<<dim3((unsigned)(cvt4 / 256)), 256, 0, stream>>>(
        token, Wp[0], Wp[1], Wp[2], XbWb, flag);
    proj_fast<<<dim3(1536), 256, 0, stream>>>(XbWb, QKV);

    float* RS = (float*)(P + (size_t)nb * pElems1);
    zero_rs_kernel<<<dim3(MROWS / 256), 256, 0, stream>>>(RS);
    for (int p = 0; p < BDIM / nb; ++p) {
        const int bbase = p * nb;
        qkt_kernel<<<dim3(nb * 1024), 256, 0, stream>>>(QKV, P, RS, bbase);
        pv_kernel<<<dim3(nb * 128), 256, 0, stream>>>(P, QKV, RS, d_out, flag, bbase);
    }
}

// Round 7
// 327.232 us; speedup vs baseline: 1.1795x; 1.0637x over previous
//
#include <hip/hip_runtime.h>
#include <stdint.h>

// ContextAttention: B=4, S=4096, D=512.
// Round 16: RESUBMIT of r15 (infra failure "container failed twice", not a
// kernel defect — source is r14 minus qkt's swizzle line; r14/r9 both ran).
//   - qkt: natural order (r14 isolated: swizzle HURT qkt, 120->140us,
//     FETCH 74->110MB — chunk put Q-panel + 4MB K slab on one L2 -> thrash).
//   - pv: XCD-chunked swizzle KEPT (r14 isolated: ~-26us — 4 n-blocks share
//     one 32MB P panel on one XCD, P fetched ~once).
// Core untouched: single-buffer m97 128x128 @256thr (proven optimum under the
// 128-reg cap; r10-r13 K-loop restructures all null/negative).
// BANNED: __launch_bounds__ (crash-assoc rounds 1-3). All grids 1-D.

#define BDIM 4
#define SDIM 4096
#define DDIM 512
#define MROWS (BDIM * SDIM)  // 16384
#define XB_ELEMS ((size_t)MROWS * DDIM)        // 8388608
#define W_ELEMS ((size_t)DDIM * DDIM)          // 262144

typedef short short8_t __attribute__((ext_vector_type(8)));
typedef short short4_t __attribute__((ext_vector_type(4)));
typedef float float4_t __attribute__((ext_vector_type(4)));

typedef __attribute__((address_space(1))) void gvoid_t;
typedef __attribute__((address_space(3))) void lvoid_t;

__device__ __forceinline__ short f2bf(float f) {
    union { float f; uint32_t u; } v; v.f = f;
    uint32_t r = v.u + 0x7FFFu + ((v.u >> 16) & 1u);  // RNE
    return (short)(r >> 16);
}
__device__ __forceinline__ float bf2f(short s) {
    union { uint32_t u; float f; } v; v.u = ((uint32_t)(uint16_t)s) << 16;
    return v.f;
}

// Storage-dtype vote (proven).
__global__ void detect_kernel(const uint32_t* __restrict__ tok, int* __restrict__ flag) {
    __shared__ int red[256];
    const int tid = threadIdx.x;
    int c = 0;
    for (int i = tid; i < 4096; i += 256) {
        uint32_t e = (tok[i] >> 7) & 0xFFu;
        c += (e >= 105u && e <= 135u) ? 1 : 0;
    }
    red[tid] = c;
    __syncthreads();
    for (int s = 128; s > 0; s >>= 1) {
        if (tid < s) red[tid] += red[tid + s];
        __syncthreads();
    }
    if (tid == 0) *flag = (red[0] > 2048) ? 1 : 0;  // 1 = bf16 storage
}

__global__ void zero_rs_kernel(float* __restrict__ RS) {
    RS[blockIdx.x * 256 + threadIdx.x] = 0.f;
}

// Pre-convert inputs to bf16: dst = Xb[8388608] | W1b | W2b | W3b (262144 ea).
__global__ void convert_kernel(const void* __restrict__ X, const void* __restrict__ W1,
                               const void* __restrict__ W2, const void* __restrict__ W3,
                               short* __restrict__ dst, const int* __restrict__ flagp)
{
    const int bf16in = *flagp;
    const size_t i4 = ((size_t)blockIdx.x * 256 + threadIdx.x) * 4;  // elem index
    const void* src; size_t off;
    if (i4 < XB_ELEMS) { src = X; off = i4; }
    else {
        const size_t j = i4 - XB_ELEMS;
        const int g = (int)(j / W_ELEMS);
        src = (g == 0) ? W1 : (g == 1) ? W2 : W3;
        off = j - (size_t)g * W_ELEMS;
    }
    if (bf16in) {
        *(short4_t*)(dst + i4) = *(const short4_t*)((const short*)src + off);
    } else {
        float4 v = *(const float4*)((const float*)src + off);
        short4_t s = { f2bf(v.x), f2bf(v.y), f2bf(v.z), f2bf(v.w) };
        *(short4_t*)(dst + i4) = s;
    }
}

// ---------------- shared m97-style GEMM core ----------------
// 128x128 tile, BK=32, unpadded LDS [128][32], staged via global_load_lds
// width=16 (wave-uniform LDS base + lane*16 == row-major 16-row chunk).
__device__ __forceinline__ void gemm_core(
    const short* __restrict__ A, int lda,
    const short* __restrict__ B, int ldb,
    int m0, int n0, int kIters,
    short* As, short* Bs, float4_t acc[4][4])
{
    const int tid = threadIdx.x;
    const int w = tid >> 6, lane = tid & 63, quad = lane >> 4, l16 = lane & 15;
    const int wm = w >> 1, wn = w & 1;
    const int rsub = lane >> 2;          // row within 16-row chunk
    const int col8 = 8 * (lane & 3);     // 8-elem (16B) column chunk

    for (int kk = 0; kk < kIters; ++kk) {
        const int k0 = 32 * kk;
        __syncthreads();
#pragma unroll
        for (int c = 0; c < 2; ++c) {
            const int row = 32 * w + 16 * c + rsub;
            const short* g = A + (size_t)(m0 + row) * lda + k0 + col8;
            __builtin_amdgcn_global_load_lds((const gvoid_t*)g,
                (lvoid_t*)(As + (32 * w + 16 * c) * 32), 16, 0, 0);
        }
#pragma unroll
        for (int c = 0; c < 2; ++c) {
            const int row = 32 * w + 16 * c + rsub;
            const short* g = B + (size_t)(n0 + row) * ldb + k0 + col8;
            __builtin_amdgcn_global_load_lds((const gvoid_t*)g,
                (lvoid_t*)(Bs + (32 * w + 16 * c) * 32), 16, 0, 0);
        }
        __syncthreads();

        short8_t af[4], bfr[4];
#pragma unroll
        for (int mt = 0; mt < 4; ++mt)
            af[mt] = *(const short8_t*)&As[(64 * wm + 16 * mt + l16) * 32 + 8 * quad];
#pragma unroll
        for (int nt = 0; nt < 4; ++nt)
            bfr[nt] = *(const short8_t*)&Bs[(64 * wn + 16 * nt + l16) * 32 + 8 * quad];
#pragma unroll
        for (int mt = 0; mt < 4; ++mt)
#pragma unroll
            for (int nt = 0; nt < 4; ++nt)
                acc[mt][nt] = __builtin_amdgcn_mfma_f32_16x16x32_bf16(af[mt], bfr[nt], acc[mt][nt], 0, 0, 0);
    }
}

// ---------------- proj (all-bf16 via Xb/Wb) ----------------
// g=0: Q = Xb @ W1b^T; g=1: K; g=2: Vt[m=e][n=bs] = W3b @ Xb^T.
__global__ void proj_fast(const short* __restrict__ XbWb, short* __restrict__ QKV)
{
    __shared__ __align__(16) short As[128 * 32];
    __shared__ __align__(16) short Bs[128 * 32];

    const short* Xb = XbWb;
    const int bid = blockIdx.x;
    const int g = bid >> 9;
    const int r = bid & 511;

    const short* Ap; const short* Bp; short* Op;
    int m0, n0, ldo;
    if (g == 2) {
        Ap = XbWb + XB_ELEMS + 2 * W_ELEMS; Bp = Xb;
        Op = QKV + 2 * (size_t)MROWS * DDIM;
        m0 = 128 * (r & 3); n0 = 128 * (r >> 2); ldo = MROWS;   // Vt[e][bs]
    } else {
        Ap = Xb; Bp = XbWb + XB_ELEMS + (size_t)g * W_ELEMS;
        Op = QKV + (size_t)g * MROWS * DDIM;
        m0 = 128 * (r >> 2); n0 = 128 * (r & 3); ldo = DDIM;    // Q/K[bs][e]
    }

    const float4_t z4 = {0.f, 0.f, 0.f, 0.f};
    float4_t acc[4][4];
#pragma unroll
    for (int i = 0; i < 4; ++i)
#pragma unroll
        for (int j = 0; j < 4; ++j) acc[i][j] = z4;

    gemm_core(Ap, DDIM, Bp, DDIM, m0, n0, 16, As, Bs, acc);

    const int tid = threadIdx.x;
    const int w = tid >> 6, lane = tid & 63, quad = lane >> 4, l16 = lane & 15;
    const int wm = w >> 1, wn = w & 1;
#pragma unroll
    for (int mt = 0; mt < 4; ++mt)
#pragma unroll
        for (int nt = 0; nt < 4; ++nt)
#pragma unroll
            for (int rr = 0; rr < 4; ++rr) {
                const int m = m0 + 64 * wm + 16 * mt + 4 * quad + rr;
                const int n = n0 + 64 * wn + 16 * nt + l16;
                Op[(size_t)m * ldo + n] = f2bf(acc[mt][nt][rr]);
            }
}

// ---------------- qkt: P = exp(sc * Q K^T) + rowsums ----------------
// Natural block order (r14 measured: XCD-chunked swizzle HURTS qkt).
__global__ void qkt_kernel(const short* __restrict__ QKV, short* __restrict__ P,
                           float* __restrict__ RS, int bbase)
{
    __shared__ __align__(16) short As[128 * 32];
    __shared__ __align__(16) short Bs[128 * 32];

    const int bid = blockIdx.x;
    const int bb = bid >> 10;
    const int r = bid & 1023;
    const int b = bbase + bb;
    const int m0 = 128 * (r >> 5);
    const int n0 = 128 * (r & 31);

    const short* Qb = QKV + (size_t)b * SDIM * DDIM;
    const short* Kb = QKV + (size_t)MROWS * DDIM + (size_t)b * SDIM * DDIM;

    const float4_t z4 = {0.f, 0.f, 0.f, 0.f};
    float4_t acc[4][4];
#pragma unroll
    for (int i = 0; i < 4; ++i)
#pragma unroll
        for (int j = 0; j < 4; ++j) acc[i][j] = z4;

    gemm_core(Qb, DDIM, Kb, DDIM, m0, n0, 16, As, Bs, acc);

    const int tid = threadIdx.x;
    const int w = tid >> 6, lane = tid & 63, quad = lane >> 4, l16 = lane & 15;
    const int wm = w >> 1, wn = w & 1;
    const float kSc = 1.44269504088896341f * 0.04419417382415922f;  // log2(e)/sqrt(512)
    short* Pb = P + (size_t)bb * SDIM * SDIM;
#pragma unroll
    for (int mt = 0; mt < 4; ++mt)
#pragma unroll
        for (int rr = 0; rr < 4; ++rr) {
            const int q = m0 + 64 * wm + 16 * mt + 4 * quad + rr;
            float sum = 0.f;
#pragma unroll
            for (int nt = 0; nt < 4; ++nt) {
                const float p = exp2f(acc[mt][nt][rr] * kSc);
                const short pb = f2bf(p);
                sum += bf2f(pb);
                Pb[(size_t)q * SDIM + n0 + 64 * wn + 16 * nt + l16] = pb;
            }
            sum += __shfl_xor(sum, 1); sum += __shfl_xor(sum, 2);
            sum += __shfl_xor(sum, 4); sum += __shfl_xor(sum, 8);
            if (l16 == 0) atomicAdd(&RS[(size_t)b * SDIM + q], sum);
        }
}

// ---------------- pv: out = (P @ Vt-rows) / RS ----------------
// Grid nb*128 (%8==0). XCD-chunked swizzle KEPT (r14 measured: ~-26us — the
// 4 n-blocks sharing a 32MB P panel land on ONE XCD -> P fetched once).
__global__ void pv_kernel(const short* __restrict__ P, const short* __restrict__ QKV,
                          const float* __restrict__ RS, void* __restrict__ out,
                          const int* __restrict__ flagp, int bbase)
{
    __shared__ __align__(16) short As[128 * 32];
    __shared__ __align__(16) short Bs[128 * 32];

    const int bf16out = *flagp;
    const int cpx = (int)(gridDim.x >> 3);          // grid % 8 == 0
    const int bid = (int)blockIdx.x;
    const int l = (bid & 7) * cpx + (bid >> 3);     // XCD chunk (T1)
    const int bb = l >> 7;
    const int r = l & 127;
    const int b = bbase + bb;
    const int m0 = 128 * (r >> 2);
    const int n0 = 128 * (r & 3);

    const short* Pb = P + (size_t)bb * SDIM * SDIM;
    const short* Vt = QKV + 2 * (size_t)MROWS * DDIM + (size_t)b * SDIM;  // rows stride MROWS

    const float4_t z4 = {0.f, 0.f, 0.f, 0.f};
    float4_t acc[4][4];
#pragma unroll
    for (int i = 0; i < 4; ++i)
#pragma unroll
        for (int j = 0; j < 4; ++j) acc[i][j] = z4;

    gemm_core(Pb, SDIM, Vt, MROWS, m0, n0, 128, As, Bs, acc);

    const int tid = threadIdx.x;
    const int w = tid >> 6, lane = tid & 63, quad = lane >> 4, l16 = lane & 15;
    const int wm = w >> 1, wn = w & 1;
#pragma unroll
    for (int mt = 0; mt < 4; ++mt)
#pragma unroll
        for (int rr = 0; rr < 4; ++rr) {
            const size_t grow = (size_t)b * SDIM + m0 + 64 * wm + 16 * mt + 4 * quad + rr;
            const float inv = 1.0f / RS[grow];
#pragma unroll
            for (int nt = 0; nt < 4; ++nt) {
                const int n = n0 + 64 * wn + 16 * nt + l16;
                const float o = acc[mt][nt][rr] * inv;
                if (bf16out) ((short*)out)[grow * DDIM + n] = f2bf(o);
                else         ((float*)out)[grow * DDIM + n] = o;
            }
        }
}

// ---------------- Fallbacks (proven round-6/8 versions) ----------------
__global__ void proj_mfma_legacy(const void* __restrict__ X, const void* __restrict__ W1,
                          const void* __restrict__ W2, const void* __restrict__ W3,
                          short* __restrict__ QKV, const int* __restrict__ flagp)
{
    __shared__ __align__(16) short As[128][40];
    __shared__ __align__(16) short Bs[128][40];

    const int bf16in = *flagp;
    const int bid = blockIdx.x;
    const int g = bid >> 9;
    const int r = bid & 511;

    const void* Ap; const void* Bp; short* Op;
    int m0, n0, ldo;
    if (g == 2) {
        Ap = W3; Bp = X; Op = QKV + 2 * (size_t)MROWS * DDIM;
        m0 = 128 * (r & 3); n0 = 128 * (r >> 2); ldo = MROWS;
    } else {
        Ap = X; Bp = (g == 0) ? W1 : W2; Op = QKV + (size_t)g * MROWS * DDIM;
        m0 = 128 * (r >> 2); n0 = 128 * (r & 3); ldo = DDIM;
    }

    const float* Af = (const float*)Ap;  const float* Bf = (const float*)Bp;
    const short* Ah = (const short*)Ap;  const short* Bh = (const short*)Bp;

    const int tid = threadIdx.x;
    const int w = tid >> 6, lane = tid & 63, quad = lane >> 4, l16 = lane & 15;
    const int wm = w >> 1, wn = w & 1;
    const int rgrp = tid >> 3, cg = tid & 7;

    const float4_t z4 = {0.f, 0.f, 0.f, 0.f};
    float4_t acc[4][4];
#pragma unroll
    for (int i = 0; i < 4; ++i)
#pragma unroll
        for (int j = 0; j < 4; ++j) acc[i][j] = z4;

    for (int kk = 0; kk < 16; ++kk) {
        const int k0 = 32 * kk;
        __syncthreads();
        if (bf16in) {
#pragma unroll
            for (int i = 0; i < 4; ++i) {
                const int row = rgrp + 32 * i;
                *(short4_t*)&As[row][4 * cg] =
                    *(const short4_t*)(Ah + (size_t)(m0 + row) * DDIM + k0 + 4 * cg);
                *(short4_t*)&Bs[row][4 * cg] =
                    *(const short4_t*)(Bh + (size_t)(n0 + row) * DDIM + k0 + 4 * cg);
            }
        } else {
#pragma unroll
            for (int i = 0; i < 4; ++i) {
                const int row = rgrp + 32 * i;
                float4 va = *(const float4*)(Af + (size_t)(m0 + row) * DDIM + k0 + 4 * cg);
                short4_t sa = { f2bf(va.x), f2bf(va.y), f2bf(va.z), f2bf(va.w) };
                *(short4_t*)&As[row][4 * cg] = sa;
                float4 vb = *(const float4*)(Bf + (size_t)(n0 + row) * DDIM + k0 + 4 * cg);
                short4_t sb = { f2bf(vb.x), f2bf(vb.y), f2bf(vb.z), f2bf(vb.w) };
                *(short4_t*)&Bs[row][4 * cg] = sb;
            }
        }
        __syncthreads();

        short8_t af[4], bfr[4];
#pragma unroll
        for (int mt = 0; mt < 4; ++mt)
            af[mt] = *(const short8_t*)&As[64 * wm + 16 * mt + l16][8 * quad];
#pragma unroll
        for (int nt = 0; nt < 4; ++nt)
            bfr[nt] = *(const short8_t*)&Bs[64 * wn + 16 * nt + l16][8 * quad];
#pragma unroll
        for (int mt = 0; mt < 4; ++mt)
#pragma unroll
            for (int nt = 0; nt < 4; ++nt)
                acc[mt][nt] = __builtin_amdgcn_mfma_f32_16x16x32_bf16(af[mt], bfr[nt], acc[mt][nt], 0, 0, 0);
    }

#pragma unroll
    for (int mt = 0; mt < 4; ++mt)
#pragma unroll
        for (int nt = 0; nt < 4; ++nt)
#pragma unroll
            for (int rr = 0; rr < 4; ++rr) {
                const int m = m0 + 64 * wm + 16 * mt + 4 * quad + rr;
                const int n = n0 + 64 * wn + 16 * nt + l16;
                Op[(size_t)m * ldo + n] = f2bf(acc[mt][nt][rr]);
            }
}

__global__ void attn_mfma(const short* __restrict__ QKV, void* __restrict__ out,
                          const int* __restrict__ flagp)
{
    __shared__ __align__(16) short Ks[32][520];
    __shared__ __align__(16) short Ps[32][72];
    __shared__ float rowsum[2][32];

    const int bf16out = *flagp;
    const short* Qb = QKV;
    const short* Kb = QKV + (size_t)MROWS * DDIM;
    const short* Vt = QKV + 2 * (size_t)MROWS * DDIM;

    const int b = blockIdx.x >> 7;
    const int q0 = (blockIdx.x & 127) * 32;
    const int tid = threadIdx.x;
    const int w = tid >> 6, lane = tid & 63, quad = lane >> 4, l16 = lane & 15;
    const int strip = w >> 1, half = w & 1;

    short8_t qf[16];
    {
        const short* qrow = Qb + (size_t)(b * SDIM + q0 + 16 * strip + l16) * DDIM + 8 * quad;
#pragma unroll
        for (int kc = 0; kc < 16; ++kc)
            qf[kc] = *(const short8_t*)(qrow + 32 * kc);
    }

    const float4_t z4 = {0.f, 0.f, 0.f, 0.f};
    float4_t o[2][8];
#pragma unroll
    for (int mt = 0; mt < 2; ++mt)
#pragma unroll
        for (int nt = 0; nt < 8; ++nt) o[mt][nt] = z4;
    float rs[4] = {0.f, 0.f, 0.f, 0.f};

    const float kSc = 1.44269504088896341f * 0.04419417382415922f;

    for (int kt = 0; kt < 128; ++kt) {
        const int kv0 = 32 * kt;
        __syncthreads();
#pragma unroll
        for (int r = 0; r < 8; ++r) {
            const int kv = 8 * w + r;
            short8_t t = *(const short8_t*)(Kb + (size_t)(b * SDIM + kv0 + kv) * DDIM + 8 * lane);
            *(short8_t*)&Ks[kv][8 * lane] = t;
        }
        __syncthreads();

        float4_t sacc = z4;
#pragma unroll
        for (int kc = 0; kc < 16; ++kc) {
            short8_t kf = *(const short8_t*)&Ks[16 * half + l16][32 * kc + 8 * quad];
            sacc = __builtin_amdgcn_mfma_f32_16x16x32_bf16(qf[kc], kf, sacc, 0, 0, 0);
        }

#pragma unroll
        for (int r = 0; r < 4; ++r) {
            const float p = exp2f(sacc[r] * kSc);
            const short pb = f2bf(p);
            rs[r] += bf2f(pb);
            Ps[16 * strip + 4 * quad + r][16 * half + l16] = pb;
        }
        __syncthreads();

        short8_t pa0 = *(const short8_t*)&Ps[l16][8 * quad];
        short8_t pa1 = *(const short8_t*)&Ps[16 + l16][8 * quad];
#pragma unroll
        for (int nt = 0; nt < 8; ++nt) {
            const short* vp = Vt + (size_t)(128 * w + 16 * nt + l16) * MROWS
                            + (b * SDIM + kv0 + 8 * quad);
            short8_t vb = *(const short8_t*)vp;
            o[0][nt] = __builtin_amdgcn_mfma_f32_16x16x32_bf16(pa0, vb, o[0][nt], 0, 0, 0);
            o[1][nt] = __builtin_amdgcn_mfma_f32_16x16x32_bf16(pa1, vb, o[1][nt], 0, 0, 0);
        }
    }

#pragma unroll
    for (int r = 0; r < 4; ++r) {
        float v = rs[r];
        v += __shfl_xor(v, 1); v += __shfl_xor(v, 2);
        v += __shfl_xor(v, 4); v += __shfl_xor(v, 8);
        rs[r] = v;
    }
    if (l16 == 0) {
#pragma unroll
        for (int r = 0; r < 4; ++r)
            rowsum[half][16 * strip + 4 * quad + r] = rs[r];
    }
    __syncthreads();

#pragma unroll
    for (int mt = 0; mt < 2; ++mt)
#pragma unroll
        for (int r = 0; r < 4; ++r) {
            const int q = 16 * mt + 4 * quad + r;
            const float inv = 1.0f / (rowsum[0][q] + rowsum[1][q]);
            const size_t base = (size_t)(b * SDIM + q0 + q) * DDIM + 128 * w + l16;
            if (bf16out) {
                short* orow = (short*)out + base;
#pragma unroll
                for (int nt = 0; nt < 8; ++nt)
                    orow[16 * nt] = f2bf(o[mt][nt][r] * inv);
            } else {
                float* orow = (float*)out + base;
#pragma unroll
                for (int nt = 0; nt < 8; ++nt)
                    orow[16 * nt] = o[mt][nt][r] * inv;
            }
        }
}

__global__ void zero_out_kernel(short* __restrict__ out, int n) {
    int i = blockIdx.x * 256 + threadIdx.x;
    if (i < n) out[i] = 0;
}

extern "C" void kernel_launch(void* const* d_in, const int* in_sizes, int n_in,
                              void* d_out, int out_size, void* d_ws, size_t ws_size,
                              hipStream_t stream) {
    const void* token = d_in[0];
    const void* Wp[3] = { d_in[1], d_in[2], d_in[3] };
    {
        int wi = 0;
        const void* tk = nullptr; const void* ws3[3] = {nullptr, nullptr, nullptr};
        bool ok = true;
        for (int i = 0; i < n_in && i < 4; ++i) {
            if (in_sizes[i] == BDIM * SDIM * DDIM) { if (tk) ok = false; tk = d_in[i]; }
            else if (in_sizes[i] == DDIM * DDIM) { if (wi < 3) ws3[wi++] = d_in[i]; else ok = false; }
            else ok = false;
        }
        if (ok && tk && wi == 3) { token = tk; Wp[0] = ws3[0]; Wp[1] = ws3[1]; Wp[2] = ws3[2]; }
    }

    const size_t qkvBytes = 3 * (size_t)MROWS * DDIM * sizeof(short);  // 48 MB
    const size_t need_base = qkvBytes + 256;
    if (ws_size < need_base) {
        zero_out_kernel<<<(out_size + 255) / 256, 256, 0, stream>>>((short*)d_out, out_size);
        return;
    }

    short* QKV = (short*)d_ws;
    int* flag = (int*)((char*)d_ws + qkvBytes);
    short* P = (short*)((char*)d_ws + need_base);   // P slab; Xb/Wb overlap (dead before qkt)
    const size_t pElems1 = (size_t)SDIM * SDIM;

    int nb = 0;
    for (int cand = 4; cand >= 1; cand >>= 1) {
        const size_t need = need_base + (size_t)cand * pElems1 * sizeof(short)
                          + (size_t)MROWS * sizeof(float);
        if (ws_size >= need) { nb = cand; break; }
    }

    detect_kernel<<<1, 256, 0, stream>>>((const uint32_t*)token, flag);

    if (nb == 0) {
        proj_mfma_legacy<<<dim3(1536), 256, 0, stream>>>(token, Wp[0], Wp[1], Wp[2], QKV, flag);
        attn_mfma<<<dim3(512), 256, 0, stream>>>(QKV, d_out, flag);
        return;
    }

    // Xb|W1b|W2b|W3b live at the head of the P slab (18.35 MB <= 32 MB min slab).
    short* XbWb = P;
    const size_t cvt4 = (XB_ELEMS + 3 * W_ELEMS) / 4;  // 2293760 lanes
    convert_kernel<<<dim3((unsigned)(cvt4 / 256)), 256, 0, stream>>>(
        token, Wp[0], Wp[1], Wp[2], XbWb, flag);
    proj_fast<<<dim3(1536), 256, 0, stream>>>(XbWb, QKV);

    float* RS = (float*)(P + (size_t)nb * pElems1);
    zero_rs_kernel<<<dim3(MROWS / 256), 256, 0, stream>>>(RS);
    for (int p = 0; p < BDIM / nb; ++p) {
        const int bbase = p * nb;
        qkt_kernel<<<dim3(nb * 1024), 256, 0, stream>>>(QKV, P, RS, bbase);
        pv_kernel<<<dim3(nb * 128), 256, 0, stream>>>(P, QKV, RS, d_out, flag, bbase);
    }
}

// Round 8
// 307.118 us; speedup vs baseline: 1.2568x; 1.0655x over previous
//
#include <hip/hip_runtime.h>
#include <stdint.h>

// ContextAttention: B=4, S=4096, D=512.
// Round 17: BK=32 -> BK=64 in the shared core (halves vmcnt(0)+barrier drains:
// qkt 16->8, pv 128->64, proj 16->8 steps) at constant 32KB LDS (occupancy
// stays reg-limited; m132's BK=128 cliff avoided). [128][64] rows = 128B would
// be a 16-way bank conflict, so BK=64 REQUIRES the both-sides XOR swizzle
// (rule #21, verified correct in r10/r11): linear LDS dest + inverse-permuted
// global source granule (scol = 8*((lane&7)^srow)) + XOR'd read granule
// ((quad+4*k2)^(l16&7)). Also kills the old 8-way conflict (8.4M cyc).
// Grid policy from r14-r16 A/B: qkt natural order, pv XCD-chunked swizzle.
// BANNED: __launch_bounds__ (crash-assoc rounds 1-3). All grids 1-D.

#define BDIM 4
#define SDIM 4096
#define DDIM 512
#define MROWS (BDIM * SDIM)  // 16384
#define XB_ELEMS ((size_t)MROWS * DDIM)        // 8388608
#define W_ELEMS ((size_t)DDIM * DDIM)          // 262144

typedef short short8_t __attribute__((ext_vector_type(8)));
typedef short short4_t __attribute__((ext_vector_type(4)));
typedef float float4_t __attribute__((ext_vector_type(4)));

typedef __attribute__((address_space(1))) void gvoid_t;
typedef __attribute__((address_space(3))) void lvoid_t;

__device__ __forceinline__ short f2bf(float f) {
    union { float f; uint32_t u; } v; v.f = f;
    uint32_t r = v.u + 0x7FFFu + ((v.u >> 16) & 1u);  // RNE
    return (short)(r >> 16);
}
__device__ __forceinline__ float bf2f(short s) {
    union { uint32_t u; float f; } v; v.u = ((uint32_t)(uint16_t)s) << 16;
    return v.f;
}

// Storage-dtype vote (proven).
__global__ void detect_kernel(const uint32_t* __restrict__ tok, int* __restrict__ flag) {
    __shared__ int red[256];
    const int tid = threadIdx.x;
    int c = 0;
    for (int i = tid; i < 4096; i += 256) {
        uint32_t e = (tok[i] >> 7) & 0xFFu;
        c += (e >= 105u && e <= 135u) ? 1 : 0;
    }
    red[tid] = c;
    __syncthreads();
    for (int s = 128; s > 0; s >>= 1) {
        if (tid < s) red[tid] += red[tid + s];
        __syncthreads();
    }
    if (tid == 0) *flag = (red[0] > 2048) ? 1 : 0;  // 1 = bf16 storage
}

__global__ void zero_rs_kernel(float* __restrict__ RS) {
    RS[blockIdx.x * 256 + threadIdx.x] = 0.f;
}

// Pre-convert inputs to bf16: dst = Xb[8388608] | W1b | W2b | W3b (262144 ea).
__global__ void convert_kernel(const void* __restrict__ X, const void* __restrict__ W1,
                               const void* __restrict__ W2, const void* __restrict__ W3,
                               short* __restrict__ dst, const int* __restrict__ flagp)
{
    const int bf16in = *flagp;
    const size_t i4 = ((size_t)blockIdx.x * 256 + threadIdx.x) * 4;  // elem index
    const void* src; size_t off;
    if (i4 < XB_ELEMS) { src = X; off = i4; }
    else {
        const size_t j = i4 - XB_ELEMS;
        const int g = (int)(j / W_ELEMS);
        src = (g == 0) ? W1 : (g == 1) ? W2 : W3;
        off = j - (size_t)g * W_ELEMS;
    }
    if (bf16in) {
        *(short4_t*)(dst + i4) = *(const short4_t*)((const short*)src + off);
    } else {
        float4 v = *(const float4*)((const float*)src + off);
        short4_t s = { f2bf(v.x), f2bf(v.y), f2bf(v.z), f2bf(v.w) };
        *(short4_t*)(dst + i4) = s;
    }
}

// ---------------- shared m97-style GEMM core, BK=64 + XOR swizzle ----------
// 128x128 tile @256thr. LDS As/Bs [128][64] (16KB ea, unpadded, linear dest).
// Stage: 4 instrs/matrix; instr c, wave w covers rows 8*(4c+w)..+7; lane ->
// (row = +lane>>3, granule = lane&7); SOURCE granule pre-swizzled:
// scol = 8*((lane&7) ^ (lane>>3))  => LDS[row][g] = glob[row][g ^ (row&7)].
// Read: granule (quad + 4*k2) ^ (l16&7) -> 2 lanes/bank (free), and the XOR
// cancels: fragment = glob[row][32*k2 + 8*quad]. 2 MFMA-K chunks per step.
__device__ __forceinline__ void gemm_core(
    const short* __restrict__ A, int lda,
    const short* __restrict__ B, int ldb,
    int m0, int n0, int kIters,
    short* As, short* Bs, float4_t acc[4][4])
{
    const int tid = threadIdx.x;
    const int w = tid >> 6, lane = tid & 63, quad = lane >> 4, l16 = lane & 15;
    const int wm = w >> 1, wn = w & 1;
    const int srow = lane >> 3;                  // row within 8-row chunk
    const int scol = 8 * ((lane & 7) ^ srow);    // inverse-swizzled source granule
    const int rsw = l16 & 7;                     // read swizzle key (row&7)

    for (int kk = 0; kk < kIters; ++kk) {
        const int k0 = 64 * kk;
        __syncthreads();
#pragma unroll
        for (int c = 0; c < 4; ++c) {
            const int rb = 8 * (4 * c + w);
            const short* g = A + (size_t)(m0 + rb + srow) * lda + k0 + scol;
            __builtin_amdgcn_global_load_lds((const gvoid_t*)g,
                (lvoid_t*)(As + rb * 64), 16, 0, 0);
        }
#pragma unroll
        for (int c = 0; c < 4; ++c) {
            const int rb = 8 * (4 * c + w);
            const short* g = B + (size_t)(n0 + rb + srow) * ldb + k0 + scol;
            __builtin_amdgcn_global_load_lds((const gvoid_t*)g,
                (lvoid_t*)(Bs + rb * 64), 16, 0, 0);
        }
        __syncthreads();

#pragma unroll
        for (int k2 = 0; k2 < 2; ++k2) {
            short8_t af[4], bfr[4];
#pragma unroll
            for (int mt = 0; mt < 4; ++mt)
                af[mt] = *(const short8_t*)&As[(64 * wm + 16 * mt + l16) * 64
                                               + 8 * ((quad + 4 * k2) ^ rsw)];
#pragma unroll
            for (int nt = 0; nt < 4; ++nt)
                bfr[nt] = *(const short8_t*)&Bs[(64 * wn + 16 * nt + l16) * 64
                                                + 8 * ((quad + 4 * k2) ^ rsw)];
#pragma unroll
            for (int mt = 0; mt < 4; ++mt)
#pragma unroll
                for (int nt = 0; nt < 4; ++nt)
                    acc[mt][nt] = __builtin_amdgcn_mfma_f32_16x16x32_bf16(af[mt], bfr[nt], acc[mt][nt], 0, 0, 0);
        }
    }
}

// ---------------- proj (all-bf16 via Xb/Wb) ----------------
// g=0: Q = Xb @ W1b^T; g=1: K; g=2: Vt[m=e][n=bs] = W3b @ Xb^T.
__global__ void proj_fast(const short* __restrict__ XbWb, short* __restrict__ QKV)
{
    __shared__ __align__(16) short As[128 * 64];
    __shared__ __align__(16) short Bs[128 * 64];

    const short* Xb = XbWb;
    const int bid = blockIdx.x;
    const int g = bid >> 9;
    const int r = bid & 511;

    const short* Ap; const short* Bp; short* Op;
    int m0, n0, ldo;
    if (g == 2) {
        Ap = XbWb + XB_ELEMS + 2 * W_ELEMS; Bp = Xb;
        Op = QKV + 2 * (size_t)MROWS * DDIM;
        m0 = 128 * (r & 3); n0 = 128 * (r >> 2); ldo = MROWS;   // Vt[e][bs]
    } else {
        Ap = Xb; Bp = XbWb + XB_ELEMS + (size_t)g * W_ELEMS;
        Op = QKV + (size_t)g * MROWS * DDIM;
        m0 = 128 * (r >> 2); n0 = 128 * (r & 3); ldo = DDIM;    // Q/K[bs][e]
    }

    const float4_t z4 = {0.f, 0.f, 0.f, 0.f};
    float4_t acc[4][4];
#pragma unroll
    for (int i = 0; i < 4; ++i)
#pragma unroll
        for (int j = 0; j < 4; ++j) acc[i][j] = z4;

    gemm_core(Ap, DDIM, Bp, DDIM, m0, n0, 8, As, Bs, acc);

    const int tid = threadIdx.x;
    const int w = tid >> 6, lane = tid & 63, quad = lane >> 4, l16 = lane & 15;
    const int wm = w >> 1, wn = w & 1;
#pragma unroll
    for (int mt = 0; mt < 4; ++mt)
#pragma unroll
        for (int nt = 0; nt < 4; ++nt)
#pragma unroll
            for (int rr = 0; rr < 4; ++rr) {
                const int m = m0 + 64 * wm + 16 * mt + 4 * quad + rr;
                const int n = n0 + 64 * wn + 16 * nt + l16;
                Op[(size_t)m * ldo + n] = f2bf(acc[mt][nt][rr]);
            }
}

// ---------------- qkt: P = exp(sc * Q K^T) + rowsums ----------------
// Natural block order (r14 measured: XCD-chunked swizzle HURTS qkt).
__global__ void qkt_kernel(const short* __restrict__ QKV, short* __restrict__ P,
                           float* __restrict__ RS, int bbase)
{
    __shared__ __align__(16) short As[128 * 64];
    __shared__ __align__(16) short Bs[128 * 64];

    const int bid = blockIdx.x;
    const int bb = bid >> 10;
    const int r = bid & 1023;
    const int b = bbase + bb;
    const int m0 = 128 * (r >> 5);
    const int n0 = 128 * (r & 31);

    const short* Qb = QKV + (size_t)b * SDIM * DDIM;
    const short* Kb = QKV + (size_t)MROWS * DDIM + (size_t)b * SDIM * DDIM;

    const float4_t z4 = {0.f, 0.f, 0.f, 0.f};
    float4_t acc[4][4];
#pragma unroll
    for (int i = 0; i < 4; ++i)
#pragma unroll
        for (int j = 0; j < 4; ++j) acc[i][j] = z4;

    gemm_core(Qb, DDIM, Kb, DDIM, m0, n0, 8, As, Bs, acc);

    const int tid = threadIdx.x;
    const int w = tid >> 6, lane = tid & 63, quad = lane >> 4, l16 = lane & 15;
    const int wm = w >> 1, wn = w & 1;
    const float kSc = 1.44269504088896341f * 0.04419417382415922f;  // log2(e)/sqrt(512)
    short* Pb = P + (size_t)bb * SDIM * SDIM;
#pragma unroll
    for (int mt = 0; mt < 4; ++mt)
#pragma unroll
        for (int rr = 0; rr < 4; ++rr) {
            const int q = m0 + 64 * wm + 16 * mt + 4 * quad + rr;
            float sum = 0.f;
#pragma unroll
            for (int nt = 0; nt < 4; ++nt) {
                const float p = exp2f(acc[mt][nt][rr] * kSc);
                const short pb = f2bf(p);
                sum += bf2f(pb);
                Pb[(size_t)q * SDIM + n0 + 64 * wn + 16 * nt + l16] = pb;
            }
            sum += __shfl_xor(sum, 1); sum += __shfl_xor(sum, 2);
            sum += __shfl_xor(sum, 4); sum += __shfl_xor(sum, 8);
            if (l16 == 0) atomicAdd(&RS[(size_t)b * SDIM + q], sum);
        }
}

// ---------------- pv: out = (P @ Vt-rows) / RS ----------------
// Grid nb*128 (%8==0). XCD-chunked swizzle KEPT (r14 measured: ~-26us — the
// 4 n-blocks sharing a 32MB P panel land on ONE XCD -> P fetched once).
__global__ void pv_kernel(const short* __restrict__ P, const short* __restrict__ QKV,
                          const float* __restrict__ RS, void* __restrict__ out,
                          const int* __restrict__ flagp, int bbase)
{
    __shared__ __align__(16) short As[128 * 64];
    __shared__ __align__(16) short Bs[128 * 64];

    const int bf16out = *flagp;
    const int cpx = (int)(gridDim.x >> 3);          // grid % 8 == 0
    const int bid = (int)blockIdx.x;
    const int l = (bid & 7) * cpx + (bid >> 3);     // XCD chunk (T1)
    const int bb = l >> 7;
    const int r = l & 127;
    const int b = bbase + bb;
    const int m0 = 128 * (r >> 2);
    const int n0 = 128 * (r & 3);

    const short* Pb = P + (size_t)bb * SDIM * SDIM;
    const short* Vt = QKV + 2 * (size_t)MROWS * DDIM + (size_t)b * SDIM;  // rows stride MROWS

    const float4_t z4 = {0.f, 0.f, 0.f, 0.f};
    float4_t acc[4][4];
#pragma unroll
    for (int i = 0; i < 4; ++i)
#pragma unroll
        for (int j = 0; j < 4; ++j) acc[i][j] = z4;

    gemm_core(Pb, SDIM, Vt, MROWS, m0, n0, 64, As, Bs, acc);

    const int tid = threadIdx.x;
    const int w = tid >> 6, lane = tid & 63, quad = lane >> 4, l16 = lane & 15;
    const int wm = w >> 1, wn = w & 1;
#pragma unroll
    for (int mt = 0; mt < 4; ++mt)
#pragma unroll
        for (int rr = 0; rr < 4; ++rr) {
            const size_t grow = (size_t)b * SDIM + m0 + 64 * wm + 16 * mt + 4 * quad + rr;
            const float inv = 1.0f / RS[grow];
#pragma unroll
            for (int nt = 0; nt < 4; ++nt) {
                const int n = n0 + 64 * wn + 16 * nt + l16;
                const float o = acc[mt][nt][rr] * inv;
                if (bf16out) ((short*)out)[grow * DDIM + n] = f2bf(o);
                else         ((float*)out)[grow * DDIM + n] = o;
            }
        }
}

// ---------------- Fallbacks (proven round-6/8 versions) ----------------
__global__ void proj_mfma_legacy(const void* __restrict__ X, const void* __restrict__ W1,
                          const void* __restrict__ W2, const void* __restrict__ W3,
                          short* __restrict__ QKV, const int* __restrict__ flagp)
{
    __shared__ __align__(16) short As[128][40];
    __shared__ __align__(16) short Bs[128][40];

    const int bf16in = *flagp;
    const int bid = blockIdx.x;
    const int g = bid >> 9;
    const int r = bid & 511;

    const void* Ap; const void* Bp; short* Op;
    int m0, n0, ldo;
    if (g == 2) {
        Ap = W3; Bp = X; Op = QKV + 2 * (size_t)MROWS * DDIM;
        m0 = 128 * (r & 3); n0 = 128 * (r >> 2); ldo = MROWS;
    } else {
        Ap = X; Bp = (g == 0) ? W1 : W2; Op = QKV + (size_t)g * MROWS * DDIM;
        m0 = 128 * (r >> 2); n0 = 128 * (r & 3); ldo = DDIM;
    }

    const float* Af = (const float*)Ap;  const float* Bf = (const float*)Bp;
    const short* Ah = (const short*)Ap;  const short* Bh = (const short*)Bp;

    const int tid = threadIdx.x;
    const int w = tid >> 6, lane = tid & 63, quad = lane >> 4, l16 = lane & 15;
    const int wm = w >> 1, wn = w & 1;
    const int rgrp = tid >> 3, cg = tid & 7;

    const float4_t z4 = {0.f, 0.f, 0.f, 0.f};
    float4_t acc[4][4];
#pragma unroll
    for (int i = 0; i < 4; ++i)
#pragma unroll
        for (int j = 0; j < 4; ++j) acc[i][j] = z4;

    for (int kk = 0; kk < 16; ++kk) {
        const int k0 = 32 * kk;
        __syncthreads();
        if (bf16in) {
#pragma unroll
            for (int i = 0; i < 4; ++i) {
                const int row = rgrp + 32 * i;
                *(short4_t*)&As[row][4 * cg] =
                    *(const short4_t*)(Ah + (size_t)(m0 + row) * DDIM + k0 + 4 * cg);
                *(short4_t*)&Bs[row][4 * cg] =
                    *(const short4_t*)(Bh + (size_t)(n0 + row) * DDIM + k0 + 4 * cg);
            }
        } else {
#pragma unroll
            for (int i = 0; i < 4; ++i) {
                const int row = rgrp + 32 * i;
                float4 va = *(const float4*)(Af + (size_t)(m0 + row) * DDIM + k0 + 4 * cg);
                short4_t sa = { f2bf(va.x), f2bf(va.y), f2bf(va.z), f2bf(va.w) };
                *(short4_t*)&As[row][4 * cg] = sa;
                float4 vb = *(const float4*)(Bf + (size_t)(n0 + row) * DDIM + k0 + 4 * cg);
                short4_t sb = { f2bf(vb.x), f2bf(vb.y), f2bf(vb.z), f2bf(vb.w) };
                *(short4_t*)&Bs[row][4 * cg] = sb;
            }
        }
        __syncthreads();

        short8_t af[4], bfr[4];
#pragma unroll
        for (int mt = 0; mt < 4; ++mt)
            af[mt] = *(const short8_t*)&As[64 * wm + 16 * mt + l16][8 * quad];
#pragma unroll
        for (int nt = 0; nt < 4; ++nt)
            bfr[nt] = *(const short8_t*)&Bs[64 * wn + 16 * nt + l16][8 * quad];
#pragma unroll
        for (int mt = 0; mt < 4; ++mt)
#pragma unroll
            for (int nt = 0; nt < 4; ++nt)
                acc[mt][nt] = __builtin_amdgcn_mfma_f32_16x16x32_bf16(af[mt], bfr[nt], acc[mt][nt], 0, 0, 0);
    }

#pragma unroll
    for (int mt = 0; mt < 4; ++mt)
#pragma unroll
        for (int nt = 0; nt < 4; ++nt)
#pragma unroll
            for (int rr = 0; rr < 4; ++rr) {
                const int m = m0 + 64 * wm + 16 * mt + 4 * quad + rr;
                const int n = n0 + 64 * wn + 16 * nt + l16;
                Op[(size_t)m * ldo + n] = f2bf(acc[mt][nt][rr]);
            }
}

__global__ void attn_mfma(const short* __restrict__ QKV, void* __restrict__ out,
                          const int* __restrict__ flagp)
{
    __shared__ __align__(16) short Ks[32][520];
    __shared__ __align__(16) short Ps[32][72];
    __shared__ float rowsum[2][32];

    const int bf16out = *flagp;
    const short* Qb = QKV;
    const short* Kb = QKV + (size_t)MROWS * DDIM;
    const short* Vt = QKV + 2 * (size_t)MROWS * DDIM;

    const int b = blockIdx.x >> 7;
    const int q0 = (blockIdx.x & 127) * 32;
    const int tid = threadIdx.x;
    const int w = tid >> 6, lane = tid & 63, quad = lane >> 4, l16 = lane & 15;
    const int strip = w >> 1, half = w & 1;

    short8_t qf[16];
    {
        const short* qrow = Qb + (size_t)(b * SDIM + q0 + 16 * strip + l16) * DDIM + 8 * quad;
#pragma unroll
        for (int kc = 0; kc < 16; ++kc)
            qf[kc] = *(const short8_t*)(qrow + 32 * kc);
    }

    const float4_t z4 = {0.f, 0.f, 0.f, 0.f};
    float4_t o[2][8];
#pragma unroll
    for (int mt = 0; mt < 2; ++mt)
#pragma unroll
        for (int nt = 0; nt < 8; ++nt) o[mt][nt] = z4;
    float rs[4] = {0.f, 0.f, 0.f, 0.f};

    const float kSc = 1.44269504088896341f * 0.04419417382415922f;

    for (int kt = 0; kt < 128; ++kt) {
        const int kv0 = 32 * kt;
        __syncthreads();
#pragma unroll
        for (int r = 0; r < 8; ++r) {
            const int kv = 8 * w + r;
            short8_t t = *(const short8_t*)(Kb + (size_t)(b * SDIM + kv0 + kv) * DDIM + 8 * lane);
            *(short8_t*)&Ks[kv][8 * lane] = t;
        }
        __syncthreads();

        float4_t sacc = z4;
#pragma unroll
        for (int kc = 0; kc < 16; ++kc) {
            short8_t kf = *(const short8_t*)&Ks[16 * half + l16][32 * kc + 8 * quad];
            sacc = __builtin_amdgcn_mfma_f32_16x16x32_bf16(qf[kc], kf, sacc, 0, 0, 0);
        }

#pragma unroll
        for (int r = 0; r < 4; ++r) {
            const float p = exp2f(sacc[r] * kSc);
            const short pb = f2bf(p);
            rs[r] += bf2f(pb);
            Ps[16 * strip + 4 * quad + r][16 * half + l16] = pb;
        }
        __syncthreads();

        short8_t pa0 = *(const short8_t*)&Ps[l16][8 * quad];
        short8_t pa1 = *(const short8_t*)&Ps[16 + l16][8 * quad];
#pragma unroll
        for (int nt = 0; nt < 8; ++nt) {
            const short* vp = Vt + (size_t)(128 * w + 16 * nt + l16) * MROWS
                            + (b * SDIM + kv0 + 8 * quad);
            short8_t vb = *(const short8_t*)vp;
            o[0][nt] = __builtin_amdgcn_mfma_f32_16x16x32_bf16(pa0, vb, o[0][nt], 0, 0, 0);
            o[1][nt] = __builtin_amdgcn_mfma_f32_16x16x32_bf16(pa1, vb, o[1][nt], 0, 0, 0);
        }
    }

#pragma unroll
    for (int r = 0; r < 4; ++r) {
        float v = rs[r];
        v += __shfl_xor(v, 1); v += __shfl_xor(v, 2);
        v += __shfl_xor(v, 4); v += __shfl_xor(v, 8);
        rs[r] = v;
    }
    if (l16 == 0) {
#pragma unroll
        for (int r = 0; r < 4; ++r)
            rowsum[half][16 * strip + 4 * quad + r] = rs[r];
    }
    __syncthreads();

#pragma unroll
    for (int mt = 0; mt < 2; ++mt)
#pragma unroll
        for (int r = 0; r < 4; ++r) {
            const int q = 16 * mt + 4 * quad + r;
            const float inv = 1.0f / (rowsum[0][q] + rowsum[1][q]);
            const size_t base = (size_t)(b * SDIM + q0 + q) * DDIM + 128 * w + l16;
            if (bf16out) {
                short* orow = (short*)out + base;
#pragma unroll
                for (int nt = 0; nt < 8; ++nt)
                    orow[16 * nt] = f2bf(o[mt][nt][r] * inv);
            } else {
                float* orow = (float*)out + base;
#pragma unroll
                for (int nt = 0; nt < 8; ++nt)
                    orow[16 * nt] = o[mt][nt][r] * inv;
            }
        }
}

__global__ void zero_out_kernel(short* __restrict__ out, int n) {
    int i = blockIdx.x * 256 + threadIdx.x;
    if (i < n) out[i] = 0;
}

extern "C" void kernel_launch(void* const* d_in, const int* in_sizes, int n_in,
                              void* d_out, int out_size, void* d_ws, size_t ws_size,
                              hipStream_t stream) {
    const void* token = d_in[0];
    const void* Wp[3] = { d_in[1], d_in[2], d_in[3] };
    {
        int wi = 0;
        const void* tk = nullptr; const void* ws3[3] = {nullptr, nullptr, nullptr};
        bool ok = true;
        for (int i = 0; i < n_in && i < 4; ++i) {
            if (in_sizes[i] == BDIM * SDIM * DDIM) { if (tk) ok = false; tk = d_in[i]; }
            else if (in_sizes[i] == DDIM * DDIM) { if (wi < 3) ws3[wi++] = d_in[i]; else ok = false; }
            else ok = false;
        }
        if (ok && tk && wi == 3) { token = tk; Wp[0] = ws3[0]; Wp[1] = ws3[1]; Wp[2] = ws3[2]; }
    }

    const size_t qkvBytes = 3 * (size_t)MROWS * DDIM * sizeof(short);  // 48 MB
    const size_t need_base = qkvBytes + 256;
    if (ws_size < need_base) {
        zero_out_kernel<<<(out_size + 255) / 256, 256, 0, stream>>>((short*)d_out, out_size);
        return;
    }

    short* QKV = (short*)d_ws;
    int* flag = (int*)((char*)d_ws + qkvBytes);
    short* P = (short*)((char*)d_ws + need_base);   // P slab; Xb/Wb overlap (dead before qkt)
    const size_t pElems1 = (size_t)SDIM * SDIM;

    int nb = 0;
    for (int cand = 4; cand >= 1; cand >>= 1) {
        const size_t need = need_base + (size_t)cand * pElems1 * sizeof(short)
                          + (size_t)MROWS * sizeof(float);
        if (ws_size >= need) { nb = cand; break; }
    }

    detect_kernel<<<1, 256, 0, stream>>>((const uint32_t*)token, flag);

    if (nb == 0) {
        proj_mfma_legacy<<<dim3(1536), 256, 0, stream>>>(token, Wp[0], Wp[1], Wp[2], QKV, flag);
        attn_mfma<<<dim3(512), 256, 0, stream>>>(QKV, d_out, flag);
        return;
    }

    // Xb|W1b|W2b|W3b live at the head of the P slab (18.35 MB <= 32 MB min slab).
    short* XbWb = P;
    const size_t cvt4 = (XB_ELEMS + 3 * W_ELEMS) / 4;  // 2293760 lanes
    convert_kernel<<<dim3((unsigned)(cvt4 / 256)), 256, 0, stream>>>(
        token, Wp[0], Wp[1], Wp[2], XbWb, flag);
    proj_fast<<<dim3(1536), 256, 0, stream>>>(XbWb, QKV);

    float* RS = (float*)(P + (size_t)nb * pElems1);
    zero_rs_kernel<<<dim3(MROWS / 256), 256, 0, stream>>>(RS);
    for (int p = 0; p < BDIM / nb; ++p) {
        const int bbase = p * nb;
        qkt_kernel<<<dim3(nb * 1024), 256, 0, stream>>>(QKV, P, RS, bbase);
        pv_kernel<<<dim3(nb * 128), 256, 0, stream>>>(P, QKV, RS, d_out, flag, bbase);
    }
}

// Round 9
// 305.895 us; speedup vs baseline: 1.2618x; 1.0040x over previous
//
#include <hip/hip_runtime.h>
#include <stdint.h>

// ContextAttention: B=4, S=4096, D=512.
// Round 18: pipeline-overhead trim. GEMM cores are AT the 2-phase structural
// ceiling (qkt 695 TF ~ m230's 682; 8-phase needs >128 reg/wave, unreachable
// under the launch_bounds ban). Changes, zero-risk:
//  1) proj reads token/W DIRECTLY when bf16in (per-block flag select) —
//     convert's bf16 path was a bit-identical copy; skip it entirely.
//  2) RS zeroing folded into convert blocks 0..63; zero_rs launch dropped.
// Core (BK=64 + both-sides XOR swizzle, r17-proven, bank-conflicts=0),
// grid policy (qkt natural / pv XCD-chunked), all else unchanged.
// BANNED: __launch_bounds__ (crash-assoc rounds 1-3). All grids 1-D.

#define BDIM 4
#define SDIM 4096
#define DDIM 512
#define MROWS (BDIM * SDIM)  // 16384
#define XB_ELEMS ((size_t)MROWS * DDIM)        // 8388608
#define W_ELEMS ((size_t)DDIM * DDIM)          // 262144

typedef short short8_t __attribute__((ext_vector_type(8)));
typedef short short4_t __attribute__((ext_vector_type(4)));
typedef float float4_t __attribute__((ext_vector_type(4)));

typedef __attribute__((address_space(1))) void gvoid_t;
typedef __attribute__((address_space(3))) void lvoid_t;

__device__ __forceinline__ short f2bf(float f) {
    union { float f; uint32_t u; } v; v.f = f;
    uint32_t r = v.u + 0x7FFFu + ((v.u >> 16) & 1u);  // RNE
    return (short)(r >> 16);
}
__device__ __forceinline__ float bf2f(short s) {
    union { uint32_t u; float f; } v; v.u = ((uint32_t)(uint16_t)s) << 16;
    return v.f;
}

// Storage-dtype vote (proven).
__global__ void detect_kernel(const uint32_t* __restrict__ tok, int* __restrict__ flag) {
    __shared__ int red[256];
    const int tid = threadIdx.x;
    int c = 0;
    for (int i = tid; i < 4096; i += 256) {
        uint32_t e = (tok[i] >> 7) & 0xFFu;
        c += (e >= 105u && e <= 135u) ? 1 : 0;
    }
    red[tid] = c;
    __syncthreads();
    for (int s = 128; s > 0; s >>= 1) {
        if (tid < s) red[tid] += red[tid + s];
        __syncthreads();
    }
    if (tid == 0) *flag = (red[0] > 2048) ? 1 : 0;  // 1 = bf16 storage
}

// Pre-convert inputs to bf16 (f32 path only; bf16 path is a no-op copy that
// proj now bypasses) + RS zeroing in blocks 0..63 (replaces zero_rs launch).
__global__ void convert_kernel(const void* __restrict__ X, const void* __restrict__ W1,
                               const void* __restrict__ W2, const void* __restrict__ W3,
                               short* __restrict__ dst, const int* __restrict__ flagp,
                               float* __restrict__ RS)
{
    const int bid = blockIdx.x;
    if (bid < 64) RS[bid * 256 + threadIdx.x] = 0.f;   // 16384 floats
    const int bf16in = *flagp;
    if (bf16in) return;                                 // proj reads raw inputs
    const size_t i4 = ((size_t)bid * 256 + threadIdx.x) * 4;  // elem index
    const void* src; size_t off;
    if (i4 < XB_ELEMS) { src = X; off = i4; }
    else {
        const size_t j = i4 - XB_ELEMS;
        const int g = (int)(j / W_ELEMS);
        src = (g == 0) ? W1 : (g == 1) ? W2 : W3;
        off = j - (size_t)g * W_ELEMS;
    }
    float4 v = *(const float4*)((const float*)src + off);
    short4_t s = { f2bf(v.x), f2bf(v.y), f2bf(v.z), f2bf(v.w) };
    *(short4_t*)(dst + i4) = s;
}

// ---------------- shared m97-style GEMM core, BK=64 + XOR swizzle ----------
// 128x128 tile @256thr. LDS As/Bs [128][64] (16KB ea, unpadded, linear dest).
// Stage: 4 instrs/matrix; instr c, wave w covers rows 8*(4c+w)..+7; lane ->
// (row = +lane>>3, granule = lane&7); SOURCE granule pre-swizzled:
// scol = 8*((lane&7) ^ (lane>>3))  => LDS[row][g] = glob[row][g ^ (row&7)].
// Read: granule (quad + 4*k2) ^ (l16&7) -> 2 lanes/bank (free), and the XOR
// cancels: fragment = glob[row][32*k2 + 8*quad]. 2 MFMA-K chunks per step.
__device__ __forceinline__ void gemm_core(
    const short* __restrict__ A, int lda,
    const short* __restrict__ B, int ldb,
    int m0, int n0, int kIters,
    short* As, short* Bs, float4_t acc[4][4])
{
    const int tid = threadIdx.x;
    const int w = tid >> 6, lane = tid & 63, quad = lane >> 4, l16 = lane & 15;
    const int wm = w >> 1, wn = w & 1;
    const int srow = lane >> 3;                  // row within 8-row chunk
    const int scol = 8 * ((lane & 7) ^ srow);    // inverse-swizzled source granule
    const int rsw = l16 & 7;                     // read swizzle key (row&7)

    for (int kk = 0; kk < kIters; ++kk) {
        const int k0 = 64 * kk;
        __syncthreads();
#pragma unroll
        for (int c = 0; c < 4; ++c) {
            const int rb = 8 * (4 * c + w);
            const short* g = A + (size_t)(m0 + rb + srow) * lda + k0 + scol;
            __builtin_amdgcn_global_load_lds((const gvoid_t*)g,
                (lvoid_t*)(As + rb * 64), 16, 0, 0);
        }
#pragma unroll
        for (int c = 0; c < 4; ++c) {
            const int rb = 8 * (4 * c + w);
            const short* g = B + (size_t)(n0 + rb + srow) * ldb + k0 + scol;
            __builtin_amdgcn_global_load_lds((const gvoid_t*)g,
                (lvoid_t*)(Bs + rb * 64), 16, 0, 0);
        }
        __syncthreads();

#pragma unroll
        for (int k2 = 0; k2 < 2; ++k2) {
            short8_t af[4], bfr[4];
#pragma unroll
            for (int mt = 0; mt < 4; ++mt)
                af[mt] = *(const short8_t*)&As[(64 * wm + 16 * mt + l16) * 64
                                               + 8 * ((quad + 4 * k2) ^ rsw)];
#pragma unroll
            for (int nt = 0; nt < 4; ++nt)
                bfr[nt] = *(const short8_t*)&Bs[(64 * wn + 16 * nt + l16) * 64
                                                + 8 * ((quad + 4 * k2) ^ rsw)];
#pragma unroll
            for (int mt = 0; mt < 4; ++mt)
#pragma unroll
                for (int nt = 0; nt < 4; ++nt)
                    acc[mt][nt] = __builtin_amdgcn_mfma_f32_16x16x32_bf16(af[mt], bfr[nt], acc[mt][nt], 0, 0, 0);
        }
    }
}

// ---------------- proj (bf16 source select: raw inputs vs converted) -------
// g=0: Q = Xb @ W1b^T; g=1: K; g=2: Vt[m=e][n=bs] = W3b @ Xb^T.
__global__ void proj_fast(const short* __restrict__ XbWb,
                          const void* __restrict__ tokRaw, const void* __restrict__ W1r,
                          const void* __restrict__ W2r, const void* __restrict__ W3r,
                          const int* __restrict__ flagp, short* __restrict__ QKV)
{
    __shared__ __align__(16) short As[128 * 64];
    __shared__ __align__(16) short Bs[128 * 64];

    const int bf16in = *flagp;
    const short* Xb = bf16in ? (const short*)tokRaw : XbWb;
    const short* Wb[3] = {
        bf16in ? (const short*)W1r : XbWb + XB_ELEMS,
        bf16in ? (const short*)W2r : XbWb + XB_ELEMS + W_ELEMS,
        bf16in ? (const short*)W3r : XbWb + XB_ELEMS + 2 * W_ELEMS };

    const int bid = blockIdx.x;
    const int g = bid >> 9;
    const int r = bid & 511;

    const short* Ap; const short* Bp; short* Op;
    int m0, n0, ldo;
    if (g == 2) {
        Ap = Wb[2]; Bp = Xb;
        Op = QKV + 2 * (size_t)MROWS * DDIM;
        m0 = 128 * (r & 3); n0 = 128 * (r >> 2); ldo = MROWS;   // Vt[e][bs]
    } else {
        Ap = Xb; Bp = Wb[g];
        Op = QKV + (size_t)g * MROWS * DDIM;
        m0 = 128 * (r >> 2); n0 = 128 * (r & 3); ldo = DDIM;    // Q/K[bs][e]
    }

    const float4_t z4 = {0.f, 0.f, 0.f, 0.f};
    float4_t acc[4][4];
#pragma unroll
    for (int i = 0; i < 4; ++i)
#pragma unroll
        for (int j = 0; j < 4; ++j) acc[i][j] = z4;

    gemm_core(Ap, DDIM, Bp, DDIM, m0, n0, 8, As, Bs, acc);

    const int tid = threadIdx.x;
    const int w = tid >> 6, lane = tid & 63, quad = lane >> 4, l16 = lane & 15;
    const int wm = w >> 1, wn = w & 1;
#pragma unroll
    for (int mt = 0; mt < 4; ++mt)
#pragma unroll
        for (int nt = 0; nt < 4; ++nt)
#pragma unroll
            for (int rr = 0; rr < 4; ++rr) {
                const int m = m0 + 64 * wm + 16 * mt + 4 * quad + rr;
                const int n = n0 + 64 * wn + 16 * nt + l16;
                Op[(size_t)m * ldo + n] = f2bf(acc[mt][nt][rr]);
            }
}

// ---------------- qkt: P = exp(sc * Q K^T) + rowsums ----------------
// Natural block order (r14 measured: XCD-chunked swizzle HURTS qkt).
__global__ void qkt_kernel(const short* __restrict__ QKV, short* __restrict__ P,
                           float* __restrict__ RS, int bbase)
{
    __shared__ __align__(16) short As[128 * 64];
    __shared__ __align__(16) short Bs[128 * 64];

    const int bid = blockIdx.x;
    const int bb = bid >> 10;
    const int r = bid & 1023;
    const int b = bbase + bb;
    const int m0 = 128 * (r >> 5);
    const int n0 = 128 * (r & 31);

    const short* Qb = QKV + (size_t)b * SDIM * DDIM;
    const short* Kb = QKV + (size_t)MROWS * DDIM + (size_t)b * SDIM * DDIM;

    const float4_t z4 = {0.f, 0.f, 0.f, 0.f};
    float4_t acc[4][4];
#pragma unroll
    for (int i = 0; i < 4; ++i)
#pragma unroll
        for (int j = 0; j < 4; ++j) acc[i][j] = z4;

    gemm_core(Qb, DDIM, Kb, DDIM, m0, n0, 8, As, Bs, acc);

    const int tid = threadIdx.x;
    const int w = tid >> 6, lane = tid & 63, quad = lane >> 4, l16 = lane & 15;
    const int wm = w >> 1, wn = w & 1;
    const float kSc = 1.44269504088896341f * 0.04419417382415922f;  // log2(e)/sqrt(512)
    short* Pb = P + (size_t)bb * SDIM * SDIM;
#pragma unroll
    for (int mt = 0; mt < 4; ++mt)
#pragma unroll
        for (int rr = 0; rr < 4; ++rr) {
            const int q = m0 + 64 * wm + 16 * mt + 4 * quad + rr;
            float sum = 0.f;
#pragma unroll
            for (int nt = 0; nt < 4; ++nt) {
                const float p = exp2f(acc[mt][nt][rr] * kSc);
                const short pb = f2bf(p);
                sum += bf2f(pb);
                Pb[(size_t)q * SDIM + n0 + 64 * wn + 16 * nt + l16] = pb;
            }
            sum += __shfl_xor(sum, 1); sum += __shfl_xor(sum, 2);
            sum += __shfl_xor(sum, 4); sum += __shfl_xor(sum, 8);
            if (l16 == 0) atomicAdd(&RS[(size_t)b * SDIM + q], sum);
        }
}

// ---------------- pv: out = (P @ Vt-rows) / RS ----------------
// Grid nb*128 (%8==0). XCD-chunked swizzle KEPT (r14 measured: ~-26us — the
// 4 n-blocks sharing a 32MB P panel land on ONE XCD -> P fetched once).
__global__ void pv_kernel(const short* __restrict__ P, const short* __restrict__ QKV,
                          const float* __restrict__ RS, void* __restrict__ out,
                          const int* __restrict__ flagp, int bbase)
{
    __shared__ __align__(16) short As[128 * 64];
    __shared__ __align__(16) short Bs[128 * 64];

    const int bf16out = *flagp;
    const int cpx = (int)(gridDim.x >> 3);          // grid % 8 == 0
    const int bid = (int)blockIdx.x;
    const int l = (bid & 7) * cpx + (bid >> 3);     // XCD chunk (T1)
    const int bb = l >> 7;
    const int r = l & 127;
    const int b = bbase + bb;
    const int m0 = 128 * (r >> 2);
    const int n0 = 128 * (r & 3);

    const short* Pb = P + (size_t)bb * SDIM * SDIM;
    const short* Vt = QKV + 2 * (size_t)MROWS * DDIM + (size_t)b * SDIM;  // rows stride MROWS

    const float4_t z4 = {0.f, 0.f, 0.f, 0.f};
    float4_t acc[4][4];
#pragma unroll
    for (int i = 0; i < 4; ++i)
#pragma unroll
        for (int j = 0; j < 4; ++j) acc[i][j] = z4;

    gemm_core(Pb, SDIM, Vt, MROWS, m0, n0, 64, As, Bs, acc);

    const int tid = threadIdx.x;
    const int w = tid >> 6, lane = tid & 63, quad = lane >> 4, l16 = lane & 15;
    const int wm = w >> 1, wn = w & 1;
#pragma unroll
    for (int mt = 0; mt < 4; ++mt)
#pragma unroll
        for (int rr = 0; rr < 4; ++rr) {
            const size_t grow = (size_t)b * SDIM + m0 + 64 * wm + 16 * mt + 4 * quad + rr;
            const float inv = 1.0f / RS[grow];
#pragma unroll
            for (int nt = 0; nt < 4; ++nt) {
                const int n = n0 + 64 * wn + 16 * nt + l16;
                const float o = acc[mt][nt][rr] * inv;
                if (bf16out) ((short*)out)[grow * DDIM + n] = f2bf(o);
                else         ((float*)out)[grow * DDIM + n] = o;
            }
        }
}

// ---------------- Fallbacks (proven round-6/8 versions) ----------------
__global__ void proj_mfma_legacy(const void* __restrict__ X, const void* __restrict__ W1,
                          const void* __restrict__ W2, const void* __restrict__ W3,
                          short* __restrict__ QKV, const int* __restrict__ flagp)
{
    __shared__ __align__(16) short As[128][40];
    __shared__ __align__(16) short Bs[128][40];

    const int bf16in = *flagp;
    const int bid = blockIdx.x;
    const int g = bid >> 9;
    const int r = bid & 511;

    const void* Ap; const void* Bp; short* Op;
    int m0, n0, ldo;
    if (g == 2) {
        Ap = W3; Bp = X; Op = QKV + 2 * (size_t)MROWS * DDIM;
        m0 = 128 * (r & 3); n0 = 128 * (r >> 2); ldo = MROWS;
    } else {
        Ap = X; Bp = (g == 0) ? W1 : W2; Op = QKV + (size_t)g * MROWS * DDIM;
        m0 = 128 * (r >> 2); n0 = 128 * (r & 3); ldo = DDIM;
    }

    const float* Af = (const float*)Ap;  const float* Bf = (const float*)Bp;
    const short* Ah = (const short*)Ap;  const short* Bh = (const short*)Bp;

    const int tid = threadIdx.x;
    const int w = tid >> 6, lane = tid & 63, quad = lane >> 4, l16 = lane & 15;
    const int wm = w >> 1, wn = w & 1;
    const int rgrp = tid >> 3, cg = tid & 7;

    const float4_t z4 = {0.f, 0.f, 0.f, 0.f};
    float4_t acc[4][4];
#pragma unroll
    for (int i = 0; i < 4; ++i)
#pragma unroll
        for (int j = 0; j < 4; ++j) acc[i][j] = z4;

    for (int kk = 0; kk < 16; ++kk) {
        const int k0 = 32 * kk;
        __syncthreads();
        if (bf16in) {
#pragma unroll
            for (int i = 0; i < 4; ++i) {
                const int row = rgrp + 32 * i;
                *(short4_t*)&As[row][4 * cg] =
                    *(const short4_t*)(Ah + (size_t)(m0 + row) * DDIM + k0 + 4 * cg);
                *(short4_t*)&Bs[row][4 * cg] =
                    *(const short4_t*)(Bh + (size_t)(n0 + row) * DDIM + k0 + 4 * cg);
            }
        } else {
#pragma unroll
            for (int i = 0; i < 4; ++i) {
                const int row = rgrp + 32 * i;
                float4 va = *(const float4*)(Af + (size_t)(m0 + row) * DDIM + k0 + 4 * cg);
                short4_t sa = { f2bf(va.x), f2bf(va.y), f2bf(va.z), f2bf(va.w) };
                *(short4_t*)&As[row][4 * cg] = sa;
                float4 vb = *(const float4*)(Bf + (size_t)(n0 + row) * DDIM + k0 + 4 * cg);
                short4_t sb = { f2bf(vb.x), f2bf(vb.y), f2bf(vb.z), f2bf(vb.w) };
                *(short4_t*)&Bs[row][4 * cg] = sb;
            }
        }
        __syncthreads();

        short8_t af[4], bfr[4];
#pragma unroll
        for (int mt = 0; mt < 4; ++mt)
            af[mt] = *(const short8_t*)&As[64 * wm + 16 * mt + l16][8 * quad];
#pragma unroll
        for (int nt = 0; nt < 4; ++nt)
            bfr[nt] = *(const short8_t*)&Bs[64 * wn + 16 * nt + l16][8 * quad];
#pragma unroll
        for (int mt = 0; mt < 4; ++mt)
#pragma unroll
            for (int nt = 0; nt < 4; ++nt)
                acc[mt][nt] = __builtin_amdgcn_mfma_f32_16x16x32_bf16(af[mt], bfr[nt], acc[mt][nt], 0, 0, 0);
    }

#pragma unroll
    for (int mt = 0; mt < 4; ++mt)
#pragma unroll
        for (int nt = 0; nt < 4; ++nt)
#pragma unroll
            for (int rr = 0; rr < 4; ++rr) {
                const int m = m0 + 64 * wm + 16 * mt + 4 * quad + rr;
                const int n = n0 + 64 * wn + 16 * nt + l16;
                Op[(size_t)m * ldo + n] = f2bf(acc[mt][nt][rr]);
            }
}

__global__ void attn_mfma(const short* __restrict__ QKV, void* __restrict__ out,
                          const int* __restrict__ flagp)
{
    __shared__ __align__(16) short Ks[32][520];
    __shared__ __align__(16) short Ps[32][72];
    __shared__ float rowsum[2][32];

    const int bf16out = *flagp;
    const short* Qb = QKV;
    const short* Kb = QKV + (size_t)MROWS * DDIM;
    const short* Vt = QKV + 2 * (size_t)MROWS * DDIM;

    const int b = blockIdx.x >> 7;
    const int q0 = (blockIdx.x & 127) * 32;
    const int tid = threadIdx.x;
    const int w = tid >> 6, lane = tid & 63, quad = lane >> 4, l16 = lane & 15;
    const int strip = w >> 1, half = w & 1;

    short8_t qf[16];
    {
        const short* qrow = Qb + (size_t)(b * SDIM + q0 + 16 * strip + l16) * DDIM + 8 * quad;
#pragma unroll
        for (int kc = 0; kc < 16; ++kc)
            qf[kc] = *(const short8_t*)(qrow + 32 * kc);
    }

    const float4_t z4 = {0.f, 0.f, 0.f, 0.f};
    float4_t o[2][8];
#pragma unroll
    for (int mt = 0; mt < 2; ++mt)
#pragma unroll
        for (int nt = 0; nt < 8; ++nt) o[mt][nt] = z4;
    float rs[4] = {0.f, 0.f, 0.f, 0.f};

    const float kSc = 1.44269504088896341f * 0.04419417382415922f;

    for (int kt = 0; kt < 128; ++kt) {
        const int kv0 = 32 * kt;
        __syncthreads();
#pragma unroll
        for (int r = 0; r < 8; ++r) {
            const int kv = 8 * w + r;
            short8_t t = *(const short8_t*)(Kb + (size_t)(b * SDIM + kv0 + kv) * DDIM + 8 * lane);
            *(short8_t*)&Ks[kv][8 * lane] = t;
        }
        __syncthreads();

        float4_t sacc = z4;
#pragma unroll
        for (int kc = 0; kc < 16; ++kc) {
            short8_t kf = *(const short8_t*)&Ks[16 * half + l16][32 * kc + 8 * quad];
            sacc = __builtin_amdgcn_mfma_f32_16x16x32_bf16(qf[kc], kf, sacc, 0, 0, 0);
        }

#pragma unroll
        for (int r = 0; r < 4; ++r) {
            const float p = exp2f(sacc[r] * kSc);
            const short pb = f2bf(p);
            rs[r] += bf2f(pb);
            Ps[16 * strip + 4 * quad + r][16 * half + l16] = pb;
        }
        __syncthreads();

        short8_t pa0 = *(const short8_t*)&Ps[l16][8 * quad];
        short8_t pa1 = *(const short8_t*)&Ps[16 + l16][8 * quad];
#pragma unroll
        for (int nt = 0; nt < 8; ++nt) {
            const short* vp = Vt + (size_t)(128 * w + 16 * nt + l16) * MROWS
                            + (b * SDIM + kv0 + 8 * quad);
            short8_t vb = *(const short8_t*)vp;
            o[0][nt] = __builtin_amdgcn_mfma_f32_16x16x32_bf16(pa0, vb, o[0][nt], 0, 0, 0);
            o[1][nt] = __builtin_amdgcn_mfma_f32_16x16x32_bf16(pa1, vb, o[1][nt], 0, 0, 0);
        }
    }

#pragma unroll
    for (int r = 0; r < 4; ++r) {
        float v = rs[r];
        v += __shfl_xor(v, 1); v += __shfl_xor(v, 2);
        v += __shfl_xor(v, 4); v += __shfl_xor(v, 8);
        rs[r] = v;
    }
    if (l16 == 0) {
#pragma unroll
        for (int r = 0; r < 4; ++r)
            rowsum[half][16 * strip + 4 * quad + r] = rs[r];
    }
    __syncthreads();

#pragma unroll
    for (int mt = 0; mt < 2; ++mt)
#pragma unroll
        for (int r = 0; r < 4; ++r) {
            const int q = 16 * mt + 4 * quad + r;
            const float inv = 1.0f / (rowsum[0][q] + rowsum[1][q]);
            const size_t base = (size_t)(b * SDIM + q0 + q) * DDIM + 128 * w + l16;
            if (bf16out) {
                short* orow = (short*)out + base;
#pragma unroll
                for (int nt = 0; nt < 8; ++nt)
                    orow[16 * nt] = f2bf(o[mt][nt][r] * inv);
            } else {
                float* orow = (float*)out + base;
#pragma unroll
                for (int nt = 0; nt < 8; ++nt)
                    orow[16 * nt] = o[mt][nt][r] * inv;
            }
        }
}

__global__ void zero_out_kernel(short* __restrict__ out, int n) {
    int i = blockIdx.x * 256 + threadIdx.x;
    if (i < n) out[i] = 0;
}

extern "C" void kernel_launch(void* const* d_in, const int* in_sizes, int n_in,
                              void* d_out, int out_size, void* d_ws, size_t ws_size,
                              hipStream_t stream) {
    const void* token = d_in[0];
    const void* Wp[3] = { d_in[1], d_in[2], d_in[3] };
    {
        int wi = 0;
        const void* tk = nullptr; const void* ws3[3] = {nullptr, nullptr, nullptr};
        bool ok = true;
        for (int i = 0; i < n_in && i < 4; ++i) {
            if (in_sizes[i] == BDIM * SDIM * DDIM) { if (tk) ok = false; tk = d_in[i]; }
            else if (in_sizes[i] == DDIM * DDIM) { if (wi < 3) ws3[wi++] = d_in[i]; else ok = false; }
            else ok = false;
        }
        if (ok && tk && wi == 3) { token = tk; Wp[0] = ws3[0]; Wp[1] = ws3[1]; Wp[2] = ws3[2]; }
    }

    const size_t qkvBytes = 3 * (size_t)MROWS * DDIM * sizeof(short);  // 48 MB
    const size_t need_base = qkvBytes + 256;
    if (ws_size < need_base) {
        zero_out_kernel<<<(out_size + 255) / 256, 256, 0, stream>>>((short*)d_out, out_size);
        return;
    }

    short* QKV = (short*)d_ws;
    int* flag = (int*)((char*)d_ws + qkvBytes);
    short* P = (short*)((char*)d_ws + need_base);   // P slab; Xb/Wb overlap (dead before qkt)
    const size_t pElems1 = (size_t)SDIM * SDIM;

    int nb = 0;
    for (int cand = 4; cand >= 1; cand >>= 1) {
        const size_t need = need_base + (size_t)cand * pElems1 * sizeof(short)
                          + (size_t)MROWS * sizeof(float);
        if (ws_size >= need) { nb = cand; break; }
    }

    detect_kernel<<<1, 256, 0, stream>>>((const uint32_t*)token, flag);

    if (nb == 0) {
        proj_mfma_legacy<<<dim3(1536), 256, 0, stream>>>(token, Wp[0], Wp[1], Wp[2], QKV, flag);
        attn_mfma<<<dim3(512), 256, 0, stream>>>(QKV, d_out, flag);
        return;
    }

    // Xb|W1b|W2b|W3b live at the head of the P slab (18.35 MB <= 32 MB min slab).
    short* XbWb = P;
    float* RS = (float*)(P + (size_t)nb * pElems1);
    const size_t cvt4 = (XB_ELEMS + 3 * W_ELEMS) / 4;  // 2293760 lanes
    convert_kernel<<<dim3((unsigned)(cvt4 / 256)), 256, 0, stream>>>(
        token, Wp[0], Wp[1], Wp[2], XbWb, flag, RS);
    proj_fast<<<dim3(1536), 256, 0, stream>>>(XbWb, token, Wp[0], Wp[1], Wp[2], flag, QKV);

    for (int p = 0; p < BDIM / nb; ++p) {
        const int bbase = p * nb;
        qkt_kernel<<<dim3(nb * 1024), 256, 0, stream>>>(QKV, P, RS, bbase);
        pv_kernel<<<dim3(nb * 128), 256, 0, stream>>>(P, QKV, RS, d_out, flag, bbase);
    }
}